// Round 1
// baseline (6485.567 us; speedup 1.0000x reference)
//
#include <hip/hip_runtime.h>
#include <hip/hip_bf16.h>

#define NN 50000
#define EE 100000
#define BB 2000
#define DIM 64
#define NF 14
#define EF 4
#define HID 128

// ---------------- weight transposes (coalesced access later) ----------------
__global__ void transpose_kernel(const float* __restrict__ gih, const float* __restrict__ ghh,
                                 const float* __restrict__ lih, const float* __restrict__ lhh,
                                 const float* __restrict__ l1,
                                 float* __restrict__ gihT, float* __restrict__ ghhT,
                                 float* __restrict__ lihT, float* __restrict__ lhhT,
                                 float* __restrict__ l1T) {
    int t = blockIdx.x * 256 + threadIdx.x;
    if (t < 192 * 64) { int j = t / 64, i = t % 64; gihT[i * 192 + j] = gih[t]; ghhT[i * 192 + j] = ghh[t]; }
    if (t < 256 * 128) { int j = t / 128, k = t % 128; lihT[k * 256 + j] = lih[t]; }
    if (t < 256 * 64) { int j = t / 64, k = t % 64; lhhT[k * 256 + j] = lhh[t]; }
    if (t < 64 * 128) { int d = t / 128, k = t % 128; l1T[k * 64 + d] = l1[t]; }
}

// ---------------- out0 = relu(x @ lin0_w.T + b) ----------------
__global__ void lin0_kernel(const float* __restrict__ x, const float* __restrict__ w,
                            const float* __restrict__ b, float* __restrict__ hv) {
    int t = blockIdx.x * 256 + threadIdx.x;
    if (t >= NN * 64) return;
    int n = t >> 6, d = t & 63;
    float acc = b[d];
    #pragma unroll
    for (int f = 0; f < NF; f++) acc += x[n * NF + f] * w[d * NF + f];
    hv[t] = fmaxf(acc, 0.f);
}

// ---------------- in-degree (clipped later) ----------------
__global__ void deg_kernel(const int* __restrict__ ei, float* __restrict__ deg) {
    int e = blockIdx.x * 256 + threadIdx.x;
    if (e < EE) atomicAdd(&deg[ei[EE + e]], 1.0f);
}

// ---------------- h_e = relu(edge_attr @ w1.T + b1)  (chunk-local) ----------------
__global__ void he_kernel(const float* __restrict__ ea, const float* __restrict__ w1,
                          const float* __restrict__ b1, float* __restrict__ he,
                          int e0, int ce) {
    int t = blockIdx.x * 256 + threadIdx.x;
    if (t >= ce * 128) return;
    int el = t >> 7, h = t & 127;
    const float4 a = *(const float4*)(ea + (size_t)(e0 + el) * 4);
    const float4 w = *(const float4*)(w1 + h * 4);
    float acc = b1[h] + a.x * w.x + a.y * w.y + a.z * w.z + a.w * w.w;
    he[t] = fmaxf(acc, 0.f);
}

// ---------------- W_e = he @ w2.T + b2  -> bf16, chunk-local ----------------
// NT GEMM, tile 128x128, K-slice 32, 8x8 microtile per thread (256 threads)
__global__ __launch_bounds__(256) void we_gemm_kernel(
    const float* __restrict__ he, const float* __restrict__ w2,
    const float* __restrict__ b2, __hip_bfloat16* __restrict__ We, int ce) {
    __shared__ float As[32 * 132];
    __shared__ float Bs[32 * 132];
    const int t = threadIdx.x;
    const int tx = t & 15, ty = t >> 4;
    const int eb = blockIdx.x * 128;   // chunk-local edge base
    const int ob = blockIdx.y * 128;   // output-column base
    float acc[8][8];
    #pragma unroll
    for (int u = 0; u < 8; u++)
        #pragma unroll
        for (int v = 0; v < 8; v++) acc[u][v] = 0.f;

    for (int kk = 0; kk < 128; kk += 32) {
        #pragma unroll
        for (int rep = 0; rep < 16; rep++) {
            int idx = rep * 256 + t;
            int h = idx & 31, r = idx >> 5;
            int le = eb + r;
            As[h * 132 + r] = (le < ce) ? he[(size_t)le * 128 + kk + h] : 0.f;
            Bs[h * 132 + r] = w2[(size_t)(ob + r) * 128 + kk + h];
        }
        __syncthreads();
        for (int h = 0; h < 32; h++) {
            float4 a0 = *(const float4*)&As[h * 132 + ty * 8];
            float4 a1 = *(const float4*)&As[h * 132 + ty * 8 + 4];
            float4 b0 = *(const float4*)&Bs[h * 132 + tx * 8];
            float4 b1 = *(const float4*)&Bs[h * 132 + tx * 8 + 4];
            float av[8] = {a0.x, a0.y, a0.z, a0.w, a1.x, a1.y, a1.z, a1.w};
            float bv[8] = {b0.x, b0.y, b0.z, b0.w, b1.x, b1.y, b1.z, b1.w};
            #pragma unroll
            for (int u = 0; u < 8; u++)
                #pragma unroll
                for (int v = 0; v < 8; v++) acc[u][v] += av[u] * bv[v];
        }
        __syncthreads();
    }
    for (int u = 0; u < 8; u++) {
        int le = eb + ty * 8 + u;
        if (le >= ce) break;
        size_t rowoff = (size_t)le * 4096 + ob + tx * 8;
        #pragma unroll
        for (int v = 0; v < 4; v++) {
            __hip_bfloat162 p;
            p.x = __float2bfloat16(acc[u][2 * v] + b2[ob + tx * 8 + 2 * v]);
            p.y = __float2bfloat16(acc[u][2 * v + 1] + b2[ob + tx * 8 + 2 * v + 1]);
            *(__hip_bfloat162*)(We + rowoff + 2 * v) = p;
        }
    }
}

// ---------------- per-edge matvec msg = out[src] @ W_e[e]; atomic scatter to agg[dst] ----------------
__global__ __launch_bounds__(256) void msg_kernel(
    const float* __restrict__ hv, const __hip_bfloat16* __restrict__ We,
    const int* __restrict__ ei, float* __restrict__ agg, int e0, int ce) {
    int wave = threadIdx.x >> 6;
    int lane = threadIdx.x & 63;
    int le = blockIdx.x * 4 + wave;
    if (le >= ce) return;
    int ge = e0 + le;
    int src = ei[ge], dst = ei[EE + ge];
    float sv = hv[(size_t)src * 64 + lane];
    const __hip_bfloat16* Wrow = We + (size_t)le * 4096;
    int half = lane >> 5;
    int d0 = (lane & 31) * 2;
    float acc0 = 0.f, acc1 = 0.f;
    for (int i0 = 0; i0 < 64; i0 += 2) {
        float s = __shfl(sv, i0 + half);
        __hip_bfloat162 w = *(const __hip_bfloat162*)(Wrow + (i0 + half) * 64 + d0);
        acc0 += s * __bfloat162float(w.x);
        acc1 += s * __bfloat162float(w.y);
    }
    acc0 += __shfl_xor(acc0, 32);
    acc1 += __shfl_xor(acc1, 32);
    if (half == 0) {
        atomicAdd(&agg[(size_t)dst * 64 + d0], acc0);
        atomicAdd(&agg[(size_t)dst * 64 + d0 + 1], acc1);
    }
}

// ---------------- m = relu(agg/deg + out @ root + conv_b) ----------------
__global__ __launch_bounds__(256) void nnconv_kernel(
    const float* __restrict__ hv, const float* __restrict__ agg,
    const float* __restrict__ deg, const float* __restrict__ root,
    const float* __restrict__ cb, float* __restrict__ mbuf) {
    int wave = threadIdx.x >> 6, lane = threadIdx.x & 63;
    int n = blockIdx.x * 4 + wave;
    if (n >= NN) return;
    float o = hv[(size_t)n * 64 + lane];
    float acc = 0.f;
    for (int i = 0; i < 64; i++) {
        float s = __shfl(o, i);
        acc += s * root[i * 64 + lane];
    }
    float dg = fmaxf(deg[n], 1.0f);
    float mv = agg[(size_t)n * 64 + lane] / dg + acc + cb[lane];
    mbuf[(size_t)n * 64 + lane] = fmaxf(mv, 0.f);
}

// ---------------- GRU gates GEMM: outg[n,j] = sum_i inp[n,i]*wT[i,j] + bias[j] ----------------
// 192 threads, 32 nodes/block, weights staged to LDS (pre-transposed in global)
__global__ __launch_bounds__(192) void gates_kernel(
    const float* __restrict__ inp, int n0, int nc,
    const float* __restrict__ wT, const float* __restrict__ bias,
    float* __restrict__ outg) {
    __shared__ float sIn[32 * 64];
    __shared__ float sW[64 * 192];
    int t = threadIdx.x;
    int nb = blockIdx.x * 32;
    for (int p = t; p < 32 * 64; p += 192) {
        int k = p >> 6;
        int nl = nb + k;
        sIn[p] = (nl < nc) ? inp[(size_t)(n0 + nl) * 64 + (p & 63)] : 0.f;
    }
    for (int p = t; p < 64 * 192; p += 192) sW[p] = wT[p];
    __syncthreads();
    float acc[32];
    float b = bias[t];
    #pragma unroll
    for (int k = 0; k < 32; k++) acc[k] = b;
    for (int i = 0; i < 64; i++) {
        float w = sW[i * 192 + t];
        #pragma unroll
        for (int k = 0; k < 32; k++) acc[k] += sIn[k * 64 + i] * w;
    }
    for (int k = 0; k < 32; k++) {
        int nl = nb + k;
        if (nl < nc) outg[(size_t)nl * 192 + t] = acc[k];
    }
}

// ---------------- GRU combine: h = (1-z)*ng + z*h ----------------
__global__ void gru_combine_kernel(const float* __restrict__ gi, const float* __restrict__ gh,
                                   float* __restrict__ hv, int n0, int nc) {
    int t = blockIdx.x * 256 + threadIdx.x;
    if (t >= nc * 64) return;
    int nl = t >> 6, d = t & 63;
    size_t base = (size_t)nl * 192;
    float ir = gi[base + d], iz = gi[base + 64 + d], inn = gi[base + 128 + d];
    float hr = gh[base + d], hz = gh[base + 64 + d], hn = gh[base + 128 + d];
    float r = 1.f / (1.f + expf(-(ir + hr)));
    float z = 1.f / (1.f + expf(-(iz + hz)));
    float ng = tanhf(inn + r * hn);
    size_t gidx = (size_t)(n0 + nl) * 64 + d;
    float h = hv[gidx];
    hv[gidx] = (1.f - z) * ng + z * h;
}

// ---------------- fused Set2Set (3 steps) + readout, one block per graph ----------------
__global__ __launch_bounds__(256) void set2set_kernel(
    const float* __restrict__ hv,
    const float* __restrict__ lihT, const float* __restrict__ lhhT,
    const float* __restrict__ l_bih, const float* __restrict__ l_bhh,
    const float* __restrict__ lin1T, const float* __restrict__ lin1_b,
    const float* __restrict__ lin2_w, const float* __restrict__ lin2_b,
    float* __restrict__ out) {
    __shared__ float outS[25 * 65];
    __shared__ float qs[128], qh[64], qc[64], gat[256], ew[32], aw[32], red[64];
    int g = blockIdx.x;
    int t = threadIdx.x;
    for (int p = t; p < 25 * 64; p += 256) {
        int j = p >> 6, i = p & 63;
        outS[j * 65 + i] = hv[(size_t)(g * 25 + j) * 64 + i];
    }
    if (t < 128) qs[t] = 0.f;
    if (t < 64) { qh[t] = 0.f; qc[t] = 0.f; }
    __syncthreads();
    for (int it = 0; it < 3; it++) {
        float acc = l_bih[t] + l_bhh[t];
        for (int k = 0; k < 128; k++) acc += qs[k] * lihT[k * 256 + t];
        for (int k = 0; k < 64; k++) acc += qh[k] * lhhT[k * 256 + t];
        gat[t] = acc;
        __syncthreads();
        if (t < 64) {
            float ig = 1.f / (1.f + expf(-gat[t]));
            float fg = 1.f / (1.f + expf(-gat[64 + t]));
            float gg = tanhf(gat[128 + t]);
            float og = 1.f / (1.f + expf(-gat[192 + t]));
            float c = fg * qc[t] + ig * gg;
            qc[t] = c;
            qh[t] = og * tanhf(c);
        }
        __syncthreads();
        if (t < 25) {
            float e = 0.f;
            for (int i = 0; i < 64; i++) e += outS[t * 65 + i] * qh[i];
            ew[t] = e;
        }
        __syncthreads();
        if (t == 0) {
            float mx = ew[0];
            for (int j = 1; j < 25; j++) mx = fmaxf(mx, ew[j]);
            float s = 0.f;
            for (int j = 0; j < 25; j++) { float a = expf(ew[j] - mx); aw[j] = a; s += a; }
            float inv = 1.f / s;
            for (int j = 0; j < 25; j++) aw[j] *= inv;
        }
        __syncthreads();
        if (t < 64) {
            float r = 0.f;
            for (int j = 0; j < 25; j++) r += aw[j] * outS[j * 65 + t];
            qs[t] = qh[t];
            qs[64 + t] = r;
        }
        __syncthreads();
    }
    if (t < 64) {
        float y1 = lin1_b[t];
        for (int k = 0; k < 128; k++) y1 += qs[k] * lin1T[k * 64 + t];
        y1 = fmaxf(y1, 0.f);
        red[t] = y1 * lin2_w[t];
    }
    __syncthreads();
    if (t == 0) {
        float y = lin2_b[0];
        for (int i = 0; i < 64; i++) y += red[i];
        out[g] = y;
    }
}

static inline int imin(int a, int b) { return a < b ? a : b; }

extern "C" void kernel_launch(void* const* d_in, const int* in_sizes, int n_in,
                              void* d_out, int out_size, void* d_ws, size_t ws_size,
                              hipStream_t stream) {
    const float* x        = (const float*)d_in[0];
    const float* ea       = (const float*)d_in[1];
    const int*   ei       = (const int*)  d_in[2];
    const float* lin0_w   = (const float*)d_in[4];
    const float* lin0_b   = (const float*)d_in[5];
    const float* mlp_w1   = (const float*)d_in[6];
    const float* mlp_b1   = (const float*)d_in[7];
    const float* mlp_w2   = (const float*)d_in[8];
    const float* mlp_b2   = (const float*)d_in[9];
    const float* root     = (const float*)d_in[10];
    const float* conv_b   = (const float*)d_in[11];
    const float* gru_wih  = (const float*)d_in[12];
    const float* gru_whh  = (const float*)d_in[13];
    const float* gru_bih  = (const float*)d_in[14];
    const float* gru_bhh  = (const float*)d_in[15];
    const float* lstm_wih = (const float*)d_in[16];
    const float* lstm_whh = (const float*)d_in[17];
    const float* lstm_bih = (const float*)d_in[18];
    const float* lstm_bhh = (const float*)d_in[19];
    const float* lin1_w   = (const float*)d_in[20];
    const float* lin1_b   = (const float*)d_in[21];
    const float* lin2_w   = (const float*)d_in[22];
    const float* lin2_b   = (const float*)d_in[23];
    float* out = (float*)d_out;

    // ---- workspace carve ----
    char* base = (char*)d_ws;
    size_t off = 0;
    auto carve = [&](size_t bytes) -> void* {
        void* r = base + off;
        off = (off + bytes + 255) & ~(size_t)255;
        return r;
    };
    float* hv   = (float*)carve((size_t)NN * 64 * 4);
    float* agg  = (float*)carve((size_t)NN * 64 * 4);
    float* mbuf = (float*)carve((size_t)NN * 64 * 4);
    float* deg  = (float*)carve((size_t)NN * 4);
    float* gihT = (float*)carve(64 * 192 * 4);
    float* ghhT = (float*)carve(64 * 192 * 4);
    float* lihT = (float*)carve(128 * 256 * 4);
    float* lhhT = (float*)carve(64 * 256 * 4);
    float* l1T  = (float*)carve(128 * 64 * 4);

    size_t remain = (ws_size > off) ? ws_size - off : 0;
    const size_t per_node = 2 * 192 * 4;          // gi + gh
    const size_t per_edge = 128 * 4 + 4096 * 2;   // he + We(bf16)
    int NC, EC;
    if (remain >= (size_t)NN * per_node + (size_t)EE * per_edge + 4096) {
        NC = NN; EC = EE;
    } else {
        size_t minE_b = (size_t)2048 * per_edge;
        if (remain > minE_b + (size_t)NN * per_node + 4096) {
            NC = NN;
            EC = (int)((remain - (size_t)NN * per_node - 4096) / per_edge);
        } else {
            EC = 2048;
            size_t left = remain > (minE_b + 4096) ? remain - minE_b - 4096 : 0;
            NC = (int)(left / per_node);
        }
        EC &= ~127; if (EC < 128) EC = 128; if (EC > EE) EC = EE;
        NC &= ~31;  if (NC < 32) NC = 32;   if (NC > NN) NC = NN;
    }
    float* gi = (float*)carve((size_t)NC * 192 * 4);
    float* gh = (float*)carve((size_t)NC * 192 * 4);
    float* heb = (float*)carve((size_t)EC * 128 * 4);
    __hip_bfloat16* We = (__hip_bfloat16*)carve((size_t)EC * 4096 * 2);

    // ---- preamble ----
    hipMemsetAsync(deg, 0, (size_t)NN * 4, stream);
    transpose_kernel<<<128, 256, 0, stream>>>(gru_wih, gru_whh, lstm_wih, lstm_whh, lin1_w,
                                              gihT, ghhT, lihT, lhhT, l1T);
    lin0_kernel<<<(NN * 64 + 255) / 256, 256, 0, stream>>>(x, lin0_w, lin0_b, hv);
    deg_kernel<<<(EE + 255) / 256, 256, 0, stream>>>(ei, deg);

    bool full_edges = (EC >= EE);
    if (full_edges) {
        he_kernel<<<(EE * 128 + 255) / 256, 256, 0, stream>>>(ea, mlp_w1, mlp_b1, heb, 0, EE);
        we_gemm_kernel<<<dim3((EE + 127) / 128, 32), 256, 0, stream>>>(heb, mlp_w2, mlp_b2, We, EE);
    }

    // ---- 3 message-passing + GRU iterations ----
    for (int it = 0; it < 3; it++) {
        hipMemsetAsync(agg, 0, (size_t)NN * 64 * 4, stream);
        if (full_edges) {
            msg_kernel<<<(EE + 3) / 4, 256, 0, stream>>>(hv, We, ei, agg, 0, EE);
        } else {
            for (int e0 = 0; e0 < EE; e0 += EC) {
                int ce = imin(EC, EE - e0);
                he_kernel<<<(ce * 128 + 255) / 256, 256, 0, stream>>>(ea, mlp_w1, mlp_b1, heb, e0, ce);
                we_gemm_kernel<<<dim3((ce + 127) / 128, 32), 256, 0, stream>>>(heb, mlp_w2, mlp_b2, We, ce);
                msg_kernel<<<(ce + 3) / 4, 256, 0, stream>>>(hv, We, ei, agg, e0, ce);
            }
        }
        nnconv_kernel<<<(NN + 3) / 4, 256, 0, stream>>>(hv, agg, deg, root, conv_b, mbuf);
        for (int n0 = 0; n0 < NN; n0 += NC) {
            int nc = imin(NC, NN - n0);
            gates_kernel<<<(nc + 31) / 32, 192, 0, stream>>>(mbuf, n0, nc, gihT, gru_bih, gi);
            gates_kernel<<<(nc + 31) / 32, 192, 0, stream>>>(hv, n0, nc, ghhT, gru_bhh, gh);
            gru_combine_kernel<<<(nc * 64 + 255) / 256, 256, 0, stream>>>(gi, gh, hv, n0, nc);
        }
    }

    // ---- Set2Set + readout ----
    set2set_kernel<<<BB, 256, 0, stream>>>(hv, lihT, lhhT, lstm_bih, lstm_bhh,
                                           l1T, lin1_b, lin2_w, lin2_b, out);
}

// Round 2
// 2305.327 us; speedup vs baseline: 2.8133x; 2.8133x over previous
//
#include <hip/hip_runtime.h>
#include <hip/hip_bf16.h>

#define NN 50000
#define EE 100000
#define BB 2000
#define DIM 64
#define NF 14
#define EF 4
#define HID 128
#define EPAD 100096  // EE rounded up to 128

typedef __attribute__((ext_vector_type(8))) short short8;   // 8 bf16 (4 VGPRs)
typedef __attribute__((ext_vector_type(4))) float floatx4;  // MFMA C/D

// ---------------- weight transposes (coalesced access later) ----------------
__global__ void transpose_kernel(const float* __restrict__ gih, const float* __restrict__ ghh,
                                 const float* __restrict__ lih, const float* __restrict__ lhh,
                                 const float* __restrict__ l1,
                                 float* __restrict__ gihT, float* __restrict__ ghhT,
                                 float* __restrict__ lihT, float* __restrict__ lhhT,
                                 float* __restrict__ l1T) {
    int t = blockIdx.x * 256 + threadIdx.x;
    if (t < 192 * 64) { int j = t / 64, i = t % 64; gihT[i * 192 + j] = gih[t]; ghhT[i * 192 + j] = ghh[t]; }
    if (t < 256 * 128) { int j = t / 128, k = t % 128; lihT[k * 256 + j] = lih[t]; }
    if (t < 256 * 64) { int j = t / 64, k = t % 64; lhhT[k * 256 + j] = lhh[t]; }
    if (t < 64 * 128) { int d = t / 128, k = t % 128; l1T[k * 64 + d] = l1[t]; }
}

// ---------------- out0 = relu(x @ lin0_w.T + b) ----------------
__global__ void lin0_kernel(const float* __restrict__ x, const float* __restrict__ w,
                            const float* __restrict__ b, float* __restrict__ hv) {
    int t = blockIdx.x * 256 + threadIdx.x;
    if (t >= NN * 64) return;
    int n = t >> 6, d = t & 63;
    float acc = b[d];
    #pragma unroll
    for (int f = 0; f < NF; f++) acc += x[n * NF + f] * w[d * NF + f];
    hv[t] = fmaxf(acc, 0.f);
}

// ---------------- in-degree ----------------
__global__ void deg_kernel(const int* __restrict__ ei, float* __restrict__ deg) {
    int e = blockIdx.x * 256 + threadIdx.x;
    if (e < EE) atomicAdd(&deg[ei[EE + e]], 1.0f);
}

// ---------------- he_bf = bf16(relu(edge_attr @ w1.T + b1)), zero-padded to EPAD ----------------
__global__ void he_bf_kernel(const float* __restrict__ ea, const float* __restrict__ w1,
                             const float* __restrict__ b1, __hip_bfloat16* __restrict__ he) {
    int t = blockIdx.x * 256 + threadIdx.x;
    if (t >= EPAD * 128) return;
    int el = t >> 7, h = t & 127;
    float acc = 0.f;
    if (el < EE) {
        const float4 a = *(const float4*)(ea + (size_t)el * 4);
        const float4 w = *(const float4*)(w1 + h * 4);
        acc = fmaxf(b1[h] + a.x * w.x + a.y * w.y + a.z * w.z + a.w * w.w, 0.f);
    }
    he[t] = __float2bfloat16(acc);
}

// ---------------- w2 -> bf16 ----------------
__global__ void w2cvt_kernel(const float* __restrict__ w2, __hip_bfloat16* __restrict__ w2bf) {
    int t = blockIdx.x * 256 + threadIdx.x;
    if (t < 4096 * 128) w2bf[t] = __float2bfloat16(w2[t]);
}

// ---------------- fused: W_e (MFMA, never stored) -> msg -> atomic scatter; + xsum scatter ----------------
// block = 256 threads = 4 waves; block covers 128 edges; wave covers 32 edges (2 M-tiles of 16).
// Per wave: A = he_bf[32x128] resident in regs; loop i=0..63 (W row idx), ob=0..3 (o-base/16):
//   C[16x16] = A-tile x w2bf-rows(c=i*64+ob*16..+15) via 4 chained mfma_f32_16x16x32_bf16,
//   then msg[e, ob*16+col] += xs[e][i] * C  (xs from LDS, broadcast reads).
__global__ __launch_bounds__(256) void msg_fused_kernel(
    const float* __restrict__ hv, const __hip_bfloat16* __restrict__ he_bf,
    const __hip_bfloat16* __restrict__ w2bf, const int* __restrict__ ei,
    float* __restrict__ agg, float* __restrict__ xsum) {
    __shared__ float sXs[128 * 65];
    __shared__ int sDst[128];
    const int t = threadIdx.x;
    const int eb = blockIdx.x * 128;

    if (t < 128) {
        int e = eb + t;
        sDst[t] = (e < EE) ? ei[EE + e] : 0;
    }
    #pragma unroll 4
    for (int rep = 0; rep < 32; rep++) {
        int el = rep * 4 + (t >> 6);
        int d = t & 63;
        int e = eb + el;
        float v = 0.f;
        if (e < EE) { int src = ei[e]; v = hv[(size_t)src * 64 + d]; }
        sXs[el * 65 + d] = v;
    }
    __syncthreads();

    const int lane = t & 63;
    const int w = t >> 6;
    const int col = lane & 15;        // A row / D col
    const int quad = lane >> 4;       // k-quad / D row-quad
    const int ebw = eb + w * 32;      // wave's global edge base

    // A fragments: he_bf[edge][k], lane holds row=col, k=ks*32+quad*8..+7
    short8 afrag[2][4];
    #pragma unroll
    for (int mt = 0; mt < 2; mt++)
        #pragma unroll
        for (int ks = 0; ks < 4; ks++)
            afrag[mt][ks] = *(const short8*)(he_bf + (size_t)(ebw + mt * 16 + col) * 128 + ks * 32 + quad * 8);

    // B base: w2bf row (c_base + col), k-offset quad*8
    const __hip_bfloat16* wp = w2bf + col * 128 + quad * 8;

    floatx4 msga[2][4];
    #pragma unroll
    for (int mt = 0; mt < 2; mt++)
        #pragma unroll
        for (int ob = 0; ob < 4; ob++)
            msga[mt][ob] = (floatx4){0.f, 0.f, 0.f, 0.f};

    const int row_local = w * 32 + quad * 4;  // + mt*16 + r = lane's D-row edges (block-local)

    #pragma unroll 1
    for (int i = 0; i < 64; i++) {
        float xs0[4], xs1[4];
        #pragma unroll
        for (int r = 0; r < 4; r++) {
            xs0[r] = sXs[(row_local + r) * 65 + i];
            xs1[r] = sXs[(row_local + 16 + r) * 65 + i];
        }
        #pragma unroll
        for (int ob = 0; ob < 4; ob++) {
            floatx4 C0 = (floatx4){0.f, 0.f, 0.f, 0.f};
            floatx4 C1 = (floatx4){0.f, 0.f, 0.f, 0.f};
            #pragma unroll
            for (int ks = 0; ks < 4; ks++) {
                short8 bfr = *(const short8*)(wp + (size_t)i * 8192 + ob * 2048 + ks * 32);
                C0 = __builtin_amdgcn_mfma_f32_16x16x32_bf16(afrag[0][ks], bfr, C0, 0, 0, 0);
                C1 = __builtin_amdgcn_mfma_f32_16x16x32_bf16(afrag[1][ks], bfr, C1, 0, 0, 0);
            }
            #pragma unroll
            for (int r = 0; r < 4; r++) {
                msga[0][ob][r] += xs0[r] * C0[r];
                msga[1][ob][r] += xs1[r] * C1[r];
            }
        }
    }

    // scatter msg -> agg
    #pragma unroll
    for (int mt = 0; mt < 2; mt++) {
        #pragma unroll
        for (int r = 0; r < 4; r++) {
            int el = w * 32 + mt * 16 + quad * 4 + r;
            int e = eb + el;
            if (e < EE) {
                float* ap = agg + (size_t)sDst[el] * 64 + col;
                #pragma unroll
                for (int ob = 0; ob < 4; ob++)
                    atomicAdd(ap + ob * 16, msga[mt][ob][r]);
            }
        }
    }
    // scatter xs -> xsum (for the b2 term, applied in nnconv)
    #pragma unroll 4
    for (int rep = 0; rep < 32; rep++) {
        int el = rep * 4 + (t >> 6);
        int d = t & 63;
        int e = eb + el;
        if (e < EE) atomicAdd(&xsum[(size_t)sDst[el] * 64 + d], sXs[el * 65 + d]);
    }
}

// ---------------- m = relu((agg + xsum@B2)/deg + out@root + conv_b) ----------------
__global__ __launch_bounds__(256) void nnconv_kernel(
    const float* __restrict__ hv, const float* __restrict__ agg,
    const float* __restrict__ xsum, const float* __restrict__ deg,
    const float* __restrict__ root, const float* __restrict__ b2,
    const float* __restrict__ cb, float* __restrict__ mbuf) {
    int wave = threadIdx.x >> 6, lane = threadIdx.x & 63;
    int n = blockIdx.x * 4 + wave;
    if (n >= NN) return;
    float o = hv[(size_t)n * 64 + lane];
    float xv = xsum[(size_t)n * 64 + lane];
    float accR = 0.f, accB = 0.f;
    for (int i = 0; i < 64; i++) {
        float s = __shfl(o, i);
        accR += s * root[i * 64 + lane];
        float sx = __shfl(xv, i);
        accB += sx * b2[i * 64 + lane];
    }
    float dg = fmaxf(deg[n], 1.0f);
    float mv = (agg[(size_t)n * 64 + lane] + accB) / dg + accR + cb[lane];
    mbuf[(size_t)n * 64 + lane] = fmaxf(mv, 0.f);
}

// ---------------- GRU gates GEMM ----------------
__global__ __launch_bounds__(192) void gates_kernel(
    const float* __restrict__ inp,
    const float* __restrict__ wT, const float* __restrict__ bias,
    float* __restrict__ outg) {
    __shared__ float sIn[32 * 64];
    __shared__ float sW[64 * 192];
    int t = threadIdx.x;
    int nb = blockIdx.x * 32;
    for (int p = t; p < 32 * 64; p += 192) {
        int k = p >> 6;
        int nl = nb + k;
        sIn[p] = (nl < NN) ? inp[(size_t)nl * 64 + (p & 63)] : 0.f;
    }
    for (int p = t; p < 64 * 192; p += 192) sW[p] = wT[p];
    __syncthreads();
    float acc[32];
    float b = bias[t];
    #pragma unroll
    for (int k = 0; k < 32; k++) acc[k] = b;
    for (int i = 0; i < 64; i++) {
        float w = sW[i * 192 + t];
        #pragma unroll
        for (int k = 0; k < 32; k++) acc[k] += sIn[k * 64 + i] * w;
    }
    for (int k = 0; k < 32; k++) {
        int nl = nb + k;
        if (nl < NN) outg[(size_t)nl * 192 + t] = acc[k];
    }
}

// ---------------- GRU combine ----------------
__global__ void gru_combine_kernel(const float* __restrict__ gi, const float* __restrict__ gh,
                                   float* __restrict__ hv) {
    int t = blockIdx.x * 256 + threadIdx.x;
    if (t >= NN * 64) return;
    int nl = t >> 6, d = t & 63;
    size_t base = (size_t)nl * 192;
    float ir = gi[base + d], iz = gi[base + 64 + d], inn = gi[base + 128 + d];
    float hr = gh[base + d], hz = gh[base + 64 + d], hn = gh[base + 128 + d];
    float r = 1.f / (1.f + expf(-(ir + hr)));
    float z = 1.f / (1.f + expf(-(iz + hz)));
    float ng = tanhf(inn + r * hn);
    float h = hv[t];
    hv[t] = (1.f - z) * ng + z * h;
}

// ---------------- fused Set2Set (3 steps) + readout, one block per graph ----------------
__global__ __launch_bounds__(256) void set2set_kernel(
    const float* __restrict__ hv,
    const float* __restrict__ lihT, const float* __restrict__ lhhT,
    const float* __restrict__ l_bih, const float* __restrict__ l_bhh,
    const float* __restrict__ lin1T, const float* __restrict__ lin1_b,
    const float* __restrict__ lin2_w, const float* __restrict__ lin2_b,
    float* __restrict__ out) {
    __shared__ float outS[25 * 65];
    __shared__ float qs[128], qh[64], qc[64], gat[256], ew[32], aw[32], red[64];
    int g = blockIdx.x;
    int t = threadIdx.x;
    for (int p = t; p < 25 * 64; p += 256) {
        int j = p >> 6, i = p & 63;
        outS[j * 65 + i] = hv[(size_t)(g * 25 + j) * 64 + i];
    }
    if (t < 128) qs[t] = 0.f;
    if (t < 64) { qh[t] = 0.f; qc[t] = 0.f; }
    __syncthreads();
    for (int it = 0; it < 3; it++) {
        float acc = l_bih[t] + l_bhh[t];
        for (int k = 0; k < 128; k++) acc += qs[k] * lihT[k * 256 + t];
        for (int k = 0; k < 64; k++) acc += qh[k] * lhhT[k * 256 + t];
        gat[t] = acc;
        __syncthreads();
        if (t < 64) {
            float ig = 1.f / (1.f + expf(-gat[t]));
            float fg = 1.f / (1.f + expf(-gat[64 + t]));
            float gg = tanhf(gat[128 + t]);
            float og = 1.f / (1.f + expf(-gat[192 + t]));
            float c = fg * qc[t] + ig * gg;
            qc[t] = c;
            qh[t] = og * tanhf(c);
        }
        __syncthreads();
        if (t < 25) {
            float e = 0.f;
            for (int i = 0; i < 64; i++) e += outS[t * 65 + i] * qh[i];
            ew[t] = e;
        }
        __syncthreads();
        if (t == 0) {
            float mx = ew[0];
            for (int j = 1; j < 25; j++) mx = fmaxf(mx, ew[j]);
            float s = 0.f;
            for (int j = 0; j < 25; j++) { float a = expf(ew[j] - mx); aw[j] = a; s += a; }
            float inv = 1.f / s;
            for (int j = 0; j < 25; j++) aw[j] *= inv;
        }
        __syncthreads();
        if (t < 64) {
            float r = 0.f;
            for (int j = 0; j < 25; j++) r += aw[j] * outS[j * 65 + t];
            qs[t] = qh[t];
            qs[64 + t] = r;
        }
        __syncthreads();
    }
    if (t < 64) {
        float y1 = lin1_b[t];
        for (int k = 0; k < 128; k++) y1 += qs[k] * lin1T[k * 64 + t];
        y1 = fmaxf(y1, 0.f);
        red[t] = y1 * lin2_w[t];
    }
    __syncthreads();
    if (t == 0) {
        float y = lin2_b[0];
        for (int i = 0; i < 64; i++) y += red[i];
        out[g] = y;
    }
}

extern "C" void kernel_launch(void* const* d_in, const int* in_sizes, int n_in,
                              void* d_out, int out_size, void* d_ws, size_t ws_size,
                              hipStream_t stream) {
    const float* x        = (const float*)d_in[0];
    const float* ea       = (const float*)d_in[1];
    const int*   ei       = (const int*)  d_in[2];
    const float* lin0_w   = (const float*)d_in[4];
    const float* lin0_b   = (const float*)d_in[5];
    const float* mlp_w1   = (const float*)d_in[6];
    const float* mlp_b1   = (const float*)d_in[7];
    const float* mlp_w2   = (const float*)d_in[8];
    const float* mlp_b2   = (const float*)d_in[9];
    const float* root     = (const float*)d_in[10];
    const float* conv_b   = (const float*)d_in[11];
    const float* gru_wih  = (const float*)d_in[12];
    const float* gru_whh  = (const float*)d_in[13];
    const float* gru_bih  = (const float*)d_in[14];
    const float* gru_bhh  = (const float*)d_in[15];
    const float* lstm_wih = (const float*)d_in[16];
    const float* lstm_whh = (const float*)d_in[17];
    const float* lstm_bih = (const float*)d_in[18];
    const float* lstm_bhh = (const float*)d_in[19];
    const float* lin1_w   = (const float*)d_in[20];
    const float* lin1_b   = (const float*)d_in[21];
    const float* lin2_w   = (const float*)d_in[22];
    const float* lin2_b   = (const float*)d_in[23];
    float* out = (float*)d_out;

    // ---- workspace carve (~156 MB total) ----
    char* base = (char*)d_ws;
    size_t off = 0;
    auto carve = [&](size_t bytes) -> void* {
        void* r = base + off;
        off = (off + bytes + 255) & ~(size_t)255;
        return r;
    };
    float* hv   = (float*)carve((size_t)NN * 64 * 4);
    float* agg  = (float*)carve((size_t)NN * 64 * 4);
    float* xsum = (float*)carve((size_t)NN * 64 * 4);
    float* mbuf = (float*)carve((size_t)NN * 64 * 4);
    float* deg  = (float*)carve((size_t)NN * 4);
    float* gihT = (float*)carve(64 * 192 * 4);
    float* ghhT = (float*)carve(64 * 192 * 4);
    float* lihT = (float*)carve(128 * 256 * 4);
    float* lhhT = (float*)carve(64 * 256 * 4);
    float* l1T  = (float*)carve(128 * 64 * 4);
    float* gi   = (float*)carve((size_t)NN * 192 * 4);
    float* gh   = (float*)carve((size_t)NN * 192 * 4);
    __hip_bfloat16* he_bf = (__hip_bfloat16*)carve((size_t)EPAD * 128 * 2);
    __hip_bfloat16* w2bf  = (__hip_bfloat16*)carve((size_t)4096 * 128 * 2);

    // ---- preamble ----
    hipMemsetAsync(deg, 0, (size_t)NN * 4, stream);
    transpose_kernel<<<128, 256, 0, stream>>>(gru_wih, gru_whh, lstm_wih, lstm_whh, lin1_w,
                                              gihT, ghhT, lihT, lhhT, l1T);
    lin0_kernel<<<(NN * 64 + 255) / 256, 256, 0, stream>>>(x, lin0_w, lin0_b, hv);
    deg_kernel<<<(EE + 255) / 256, 256, 0, stream>>>(ei, deg);
    he_bf_kernel<<<(EPAD * 128 + 255) / 256, 256, 0, stream>>>(ea, mlp_w1, mlp_b1, he_bf);
    w2cvt_kernel<<<(4096 * 128 + 255) / 256, 256, 0, stream>>>(mlp_w2, w2bf);

    // ---- 3 message-passing + GRU iterations ----
    for (int it = 0; it < 3; it++) {
        hipMemsetAsync(agg, 0, (size_t)NN * 64 * 4, stream);
        hipMemsetAsync(xsum, 0, (size_t)NN * 64 * 4, stream);
        msg_fused_kernel<<<EPAD / 128, 256, 0, stream>>>(hv, he_bf, w2bf, ei, agg, xsum);
        nnconv_kernel<<<(NN + 3) / 4, 256, 0, stream>>>(hv, agg, xsum, deg, root, mlp_b2, conv_b, mbuf);
        gates_kernel<<<(NN + 31) / 32, 192, 0, stream>>>(mbuf, gihT, gru_bih, gi);
        gates_kernel<<<(NN + 31) / 32, 192, 0, stream>>>(hv, ghhT, gru_bhh, gh);
        gru_combine_kernel<<<(NN * 64 + 255) / 256, 256, 0, stream>>>(gi, gh, hv);
    }

    // ---- Set2Set + readout ----
    set2set_kernel<<<BB, 256, 0, stream>>>(hv, lihT, lhhT, lstm_bih, lstm_bhh,
                                           l1T, lin1_b, lin2_w, lin2_b, out);
}

// Round 3
// 1229.919 us; speedup vs baseline: 5.2732x; 1.8744x over previous
//
#include <hip/hip_runtime.h>
#include <hip/hip_bf16.h>

#define NN 50000
#define EE 100000
#define BB 2000
#define DIM 64
#define NF 14
#define EF 4
#define HID 128
#define EPAD 100096  // 391 * 256

typedef __attribute__((ext_vector_type(8))) _Float16 half8;   // 4 VGPRs
typedef __attribute__((ext_vector_type(4))) _Float16 half4;
typedef __attribute__((ext_vector_type(4))) float floatx4;    // MFMA C/D

// ---------------- weight transposes ----------------
__global__ void transpose_kernel(const float* __restrict__ gih, const float* __restrict__ ghh,
                                 const float* __restrict__ lih, const float* __restrict__ lhh,
                                 const float* __restrict__ l1,
                                 float* __restrict__ gihT, float* __restrict__ ghhT,
                                 float* __restrict__ lihT, float* __restrict__ lhhT,
                                 float* __restrict__ l1T) {
    int t = blockIdx.x * 256 + threadIdx.x;
    if (t < 192 * 64) { int j = t / 64, i = t % 64; gihT[i * 192 + j] = gih[t]; ghhT[i * 192 + j] = ghh[t]; }
    if (t < 256 * 128) { int j = t / 128, k = t % 128; lihT[k * 256 + j] = lih[t]; }
    if (t < 256 * 64) { int j = t / 64, k = t % 64; lhhT[k * 256 + j] = lhh[t]; }
    if (t < 64 * 128) { int d = t / 128, k = t % 128; l1T[k * 64 + d] = l1[t]; }
}

// ---------------- out0 = relu(x @ lin0_w.T + b) ----------------
__global__ void lin0_kernel(const float* __restrict__ x, const float* __restrict__ w,
                            const float* __restrict__ b, float* __restrict__ hv) {
    int t = blockIdx.x * 256 + threadIdx.x;
    if (t >= NN * 64) return;
    int n = t >> 6, d = t & 63;
    float acc = b[d];
    #pragma unroll
    for (int f = 0; f < NF; f++) acc += x[n * NF + f] * w[d * NF + f];
    hv[t] = fmaxf(acc, 0.f);
}

// ---------------- in-degree ----------------
__global__ void deg_kernel(const int* __restrict__ ei, float* __restrict__ deg) {
    int e = blockIdx.x * 256 + threadIdx.x;
    if (e < EE) atomicAdd(&deg[ei[EE + e]], 1.0f);
}

// ---------------- he16 = fp16(relu(edge_attr @ w1.T + b1)), zero-padded to EPAD ----------------
__global__ void he16_kernel(const float* __restrict__ ea, const float* __restrict__ w1,
                            const float* __restrict__ b1, _Float16* __restrict__ he) {
    int t = blockIdx.x * 256 + threadIdx.x;
    if (t >= EPAD * 128) return;
    int el = t >> 7, h = t & 127;
    float acc = 0.f;
    if (el < EE) {
        const float4 a = *(const float4*)(ea + (size_t)el * 4);
        const float4 w = *(const float4*)(w1 + h * 4);
        acc = fmaxf(b1[h] + a.x * w.x + a.y * w.y + a.z * w.z + a.w * w.w, 0.f);
    }
    he[t] = (_Float16)acc;
}

// ---------------- W2rT[o][i*128+h] = fp16(mlp_w2[(i*64+o)*128 + h]) ----------------
__global__ void w2rt_kernel(const float* __restrict__ w2, _Float16* __restrict__ W2rT) {
    int t = blockIdx.x * 256 + threadIdx.x;
    if (t >= 64 * 8192) return;
    int o = t >> 13, k = t & 8191, i = k >> 7, h = k & 127;
    W2rT[(size_t)o * 8192 + k] = (_Float16)w2[(size_t)(i * 64 + o) * 128 + h];
}

// ---------------- msg GEMM: msg = G @ W2rT^T, G generated in-register ----------------
// block = 256 threads = 4 waves, 256 edges (64/wave, mt=4 M-tiles of 16), N=64 (nt=4), K=8192.
// B (W2rT) streamed through double-buffered LDS in 128-k chunks (one i per chunk).
// A frag = heReg (resident) * xs scalar (fp16 pk_mul). Epilogue: atomic scatter to agg + xsum.
__global__ __launch_bounds__(256, 2) void msg_gemm_kernel(
    const float* __restrict__ hv, const _Float16* __restrict__ he16,
    const _Float16* __restrict__ W2rT, const int* __restrict__ ei,
    float* __restrict__ agg, float* __restrict__ xsum) {
    __shared__ _Float16 sB[2][64 * 136];   // padded row stride 136
    __shared__ _Float16 sXs[256 * 68];     // [edge][i], padded stride 68
    __shared__ int sDst[256];
    const int t = threadIdx.x;
    const int eb = blockIdx.x * 256;
    const int lane = t & 63;
    const int w = t >> 6;
    const int col = lane & 15;
    const int quad = lane >> 4;

    if (t < 256) {
        int e = eb + t;
        sDst[t] = (e < EE) ? ei[EE + e] : 0;
    }
    // stage xs (fp16) : 256 edges x 64 dims
    #pragma unroll 4
    for (int rep = 0; rep < 16; rep++) {
        int idx = rep * 256 + t;
        int el = idx >> 4, d4 = idx & 15;
        int e = eb + el;
        float4 v = {0.f, 0.f, 0.f, 0.f};
        if (e < EE) {
            int src = ei[e];
            v = *(const float4*)(hv + (size_t)src * 64 + d4 * 4);
        }
        half4 h4 = {(_Float16)v.x, (_Float16)v.y, (_Float16)v.z, (_Float16)v.w};
        *(half4*)&sXs[el * 68 + d4 * 4] = h4;
    }

    // resident he fragments: heReg[mt][p] = he16[row][p*32 + quad*8 .. +7]
    half8 heReg[4][4];
    #pragma unroll
    for (int mt = 0; mt < 4; mt++) {
        int row = eb + w * 64 + mt * 16 + col;
        #pragma unroll
        for (int p = 0; p < 4; p++)
            heReg[mt][p] = *(const half8*)(he16 + (size_t)row * 128 + p * 32 + quad * 8);
    }

    floatx4 Cacc[4][4];
    #pragma unroll
    for (int mt = 0; mt < 4; mt++)
        #pragma unroll
        for (int nt = 0; nt < 4; nt++)
            Cacc[mt][nt] = (floatx4){0.f, 0.f, 0.f, 0.f};

    half8 pre[4];
    const int so = t >> 4;       // staging row 0..15 (x16 reps -> 64 rows via idx)
    // staging helpers: 4 reps cover 64 rows x 16 segs of 16B
    {
        #pragma unroll
        for (int rep = 0; rep < 4; rep++) {
            int idx = rep * 256 + t;
            int o = idx >> 4, sg = idx & 15;
            pre[rep] = *(const half8*)(W2rT + (size_t)o * 8192 + 0 * 128 + sg * 8);
        }
        #pragma unroll
        for (int rep = 0; rep < 4; rep++) {
            int idx = rep * 256 + t;
            int o = idx >> 4, sg = idx & 15;
            *(half8*)&sB[0][o * 136 + sg * 8] = pre[rep];
        }
    }
    __syncthreads();

    #pragma unroll 1
    for (int i = 0; i < 64; i++) {
        int buf = i & 1;
        if (i < 63) {
            #pragma unroll
            for (int rep = 0; rep < 4; rep++) {
                int idx = rep * 256 + t;
                int o = idx >> 4, sg = idx & 15;
                pre[rep] = *(const half8*)(W2rT + (size_t)o * 8192 + (i + 1) * 128 + sg * 8);
            }
        }
        _Float16 xsx[4];
        #pragma unroll
        for (int mt = 0; mt < 4; mt++)
            xsx[mt] = sXs[(w * 64 + mt * 16 + col) * 68 + i];
        #pragma unroll
        for (int ks = 0; ks < 4; ks++) {
            half8 bfr[4];
            #pragma unroll
            for (int nt = 0; nt < 4; nt++)
                bfr[nt] = *(const half8*)&sB[buf][(nt * 16 + col) * 136 + ks * 32 + quad * 8];
            #pragma unroll
            for (int mt = 0; mt < 4; mt++) {
                half8 afr = heReg[mt][ks] * xsx[mt];
                #pragma unroll
                for (int nt = 0; nt < 4; nt++)
                    Cacc[mt][nt] = __builtin_amdgcn_mfma_f32_16x16x32_f16(afr, bfr[nt], Cacc[mt][nt], 0, 0, 0);
            }
        }
        if (i < 63) {
            #pragma unroll
            for (int rep = 0; rep < 4; rep++) {
                int idx = rep * 256 + t;
                int o = idx >> 4, sg = idx & 15;
                *(half8*)&sB[buf ^ 1][o * 136 + sg * 8] = pre[rep];
            }
        }
        __syncthreads();
    }

    // epilogue: scatter msg (C layout: row = quad*4 + r, col = col)
    #pragma unroll
    for (int mt = 0; mt < 4; mt++) {
        #pragma unroll
        for (int r = 0; r < 4; r++) {
            int el = w * 64 + mt * 16 + quad * 4 + r;
            if (eb + el < EE) {
                float* ap = agg + (size_t)sDst[el] * 64 + col;
                #pragma unroll
                for (int nt = 0; nt < 4; nt++)
                    atomicAdd(ap + nt * 16, Cacc[mt][nt][r]);
            }
        }
    }
    // scatter xs -> xsum (b2 term, applied in nnconv)
    #pragma unroll 4
    for (int rep = 0; rep < 64; rep++) {
        int idx = rep * 256 + t;
        int el = idx >> 6, d = idx & 63;
        if (eb + el < EE)
            atomicAdd(&xsum[(size_t)sDst[el] * 64 + d], (float)sXs[el * 68 + d]);
    }
    (void)so;
}

// ---------------- m = relu((agg + xsum@B2)/deg + out@root + conv_b) ----------------
__global__ __launch_bounds__(256) void nnconv_kernel(
    const float* __restrict__ hv, const float* __restrict__ agg,
    const float* __restrict__ xsum, const float* __restrict__ deg,
    const float* __restrict__ root, const float* __restrict__ b2,
    const float* __restrict__ cb, float* __restrict__ mbuf) {
    int wave = threadIdx.x >> 6, lane = threadIdx.x & 63;
    int n = blockIdx.x * 4 + wave;
    if (n >= NN) return;
    float o = hv[(size_t)n * 64 + lane];
    float xv = xsum[(size_t)n * 64 + lane];
    float accR = 0.f, accB = 0.f;
    for (int i = 0; i < 64; i++) {
        float s = __shfl(o, i);
        accR += s * root[i * 64 + lane];
        float sx = __shfl(xv, i);
        accB += sx * b2[i * 64 + lane];
    }
    float dg = fmaxf(deg[n], 1.0f);
    float mv = (agg[(size_t)n * 64 + lane] + accB) / dg + accR + cb[lane];
    mbuf[(size_t)n * 64 + lane] = fmaxf(mv, 0.f);
}

// ---------------- GRU gates GEMM ----------------
__global__ __launch_bounds__(192) void gates_kernel(
    const float* __restrict__ inp,
    const float* __restrict__ wT, const float* __restrict__ bias,
    float* __restrict__ outg) {
    __shared__ float sIn[32 * 64];
    __shared__ float sW[64 * 192];
    int t = threadIdx.x;
    int nb = blockIdx.x * 32;
    for (int p = t; p < 32 * 64; p += 192) {
        int k = p >> 6;
        int nl = nb + k;
        sIn[p] = (nl < NN) ? inp[(size_t)nl * 64 + (p & 63)] : 0.f;
    }
    for (int p = t; p < 64 * 192; p += 192) sW[p] = wT[p];
    __syncthreads();
    float acc[32];
    float b = bias[t];
    #pragma unroll
    for (int k = 0; k < 32; k++) acc[k] = b;
    for (int i = 0; i < 64; i++) {
        float w = sW[i * 192 + t];
        #pragma unroll
        for (int k = 0; k < 32; k++) acc[k] += sIn[k * 64 + i] * w;
    }
    for (int k = 0; k < 32; k++) {
        int nl = nb + k;
        if (nl < NN) outg[(size_t)nl * 192 + t] = acc[k];
    }
}

// ---------------- GRU combine ----------------
__global__ void gru_combine_kernel(const float* __restrict__ gi, const float* __restrict__ gh,
                                   float* __restrict__ hv) {
    int t = blockIdx.x * 256 + threadIdx.x;
    if (t >= NN * 64) return;
    int nl = t >> 6, d = t & 63;
    size_t base = (size_t)nl * 192;
    float ir = gi[base + d], iz = gi[base + 64 + d], inn = gi[base + 128 + d];
    float hr = gh[base + d], hz = gh[base + 64 + d], hn = gh[base + 128 + d];
    float r = 1.f / (1.f + expf(-(ir + hr)));
    float z = 1.f / (1.f + expf(-(iz + hz)));
    float ng = tanhf(inn + r * hn);
    float h = hv[t];
    hv[t] = (1.f - z) * ng + z * h;
}

// ---------------- fused Set2Set (3 steps) + readout, one block per graph ----------------
__global__ __launch_bounds__(256) void set2set_kernel(
    const float* __restrict__ hv,
    const float* __restrict__ lihT, const float* __restrict__ lhhT,
    const float* __restrict__ l_bih, const float* __restrict__ l_bhh,
    const float* __restrict__ lin1T, const float* __restrict__ lin1_b,
    const float* __restrict__ lin2_w, const float* __restrict__ lin2_b,
    float* __restrict__ out) {
    __shared__ float outS[25 * 65];
    __shared__ float qs[128], qh[64], qc[64], gat[256], ew[32], aw[32], red[64];
    int g = blockIdx.x;
    int t = threadIdx.x;
    for (int p = t; p < 25 * 64; p += 256) {
        int j = p >> 6, i = p & 63;
        outS[j * 65 + i] = hv[(size_t)(g * 25 + j) * 64 + i];
    }
    if (t < 128) qs[t] = 0.f;
    if (t < 64) { qh[t] = 0.f; qc[t] = 0.f; }
    __syncthreads();
    for (int it = 0; it < 3; it++) {
        float acc = l_bih[t] + l_bhh[t];
        for (int k = 0; k < 128; k++) acc += qs[k] * lihT[k * 256 + t];
        for (int k = 0; k < 64; k++) acc += qh[k] * lhhT[k * 256 + t];
        gat[t] = acc;
        __syncthreads();
        if (t < 64) {
            float ig = 1.f / (1.f + expf(-gat[t]));
            float fg = 1.f / (1.f + expf(-gat[64 + t]));
            float gg = tanhf(gat[128 + t]);
            float og = 1.f / (1.f + expf(-gat[192 + t]));
            float c = fg * qc[t] + ig * gg;
            qc[t] = c;
            qh[t] = og * tanhf(c);
        }
        __syncthreads();
        if (t < 25) {
            float e = 0.f;
            for (int i = 0; i < 64; i++) e += outS[t * 65 + i] * qh[i];
            ew[t] = e;
        }
        __syncthreads();
        if (t == 0) {
            float mx = ew[0];
            for (int j = 1; j < 25; j++) mx = fmaxf(mx, ew[j]);
            float s = 0.f;
            for (int j = 0; j < 25; j++) { float a = expf(ew[j] - mx); aw[j] = a; s += a; }
            float inv = 1.f / s;
            for (int j = 0; j < 25; j++) aw[j] *= inv;
        }
        __syncthreads();
        if (t < 64) {
            float r = 0.f;
            for (int j = 0; j < 25; j++) r += aw[j] * outS[j * 65 + t];
            qs[t] = qh[t];
            qs[64 + t] = r;
        }
        __syncthreads();
    }
    if (t < 64) {
        float y1 = lin1_b[t];
        for (int k = 0; k < 128; k++) y1 += qs[k] * lin1T[k * 64 + t];
        y1 = fmaxf(y1, 0.f);
        red[t] = y1 * lin2_w[t];
    }
    __syncthreads();
    if (t == 0) {
        float y = lin2_b[0];
        for (int i = 0; i < 64; i++) y += red[i];
        out[g] = y;
    }
}

extern "C" void kernel_launch(void* const* d_in, const int* in_sizes, int n_in,
                              void* d_out, int out_size, void* d_ws, size_t ws_size,
                              hipStream_t stream) {
    const float* x        = (const float*)d_in[0];
    const float* ea       = (const float*)d_in[1];
    const int*   ei       = (const int*)  d_in[2];
    const float* lin0_w   = (const float*)d_in[4];
    const float* lin0_b   = (const float*)d_in[5];
    const float* mlp_w1   = (const float*)d_in[6];
    const float* mlp_b1   = (const float*)d_in[7];
    const float* mlp_w2   = (const float*)d_in[8];
    const float* mlp_b2   = (const float*)d_in[9];
    const float* root     = (const float*)d_in[10];
    const float* conv_b   = (const float*)d_in[11];
    const float* gru_wih  = (const float*)d_in[12];
    const float* gru_whh  = (const float*)d_in[13];
    const float* gru_bih  = (const float*)d_in[14];
    const float* gru_bhh  = (const float*)d_in[15];
    const float* lstm_wih = (const float*)d_in[16];
    const float* lstm_whh = (const float*)d_in[17];
    const float* lstm_bih = (const float*)d_in[18];
    const float* lstm_bhh = (const float*)d_in[19];
    const float* lin1_w   = (const float*)d_in[20];
    const float* lin1_b   = (const float*)d_in[21];
    const float* lin2_w   = (const float*)d_in[22];
    const float* lin2_b   = (const float*)d_in[23];
    float* out = (float*)d_out;

    // ---- workspace carve ----
    char* base = (char*)d_ws;
    size_t off = 0;
    auto carve = [&](size_t bytes) -> void* {
        void* r = base + off;
        off = (off + bytes + 255) & ~(size_t)255;
        return r;
    };
    float* hv   = (float*)carve((size_t)NN * 64 * 4);
    float* agg  = (float*)carve((size_t)NN * 64 * 4);
    float* xsum = (float*)carve((size_t)NN * 64 * 4);
    float* mbuf = (float*)carve((size_t)NN * 64 * 4);
    float* deg  = (float*)carve((size_t)NN * 4);
    float* gihT = (float*)carve(64 * 192 * 4);
    float* ghhT = (float*)carve(64 * 192 * 4);
    float* lihT = (float*)carve(128 * 256 * 4);
    float* lhhT = (float*)carve(64 * 256 * 4);
    float* l1T  = (float*)carve(128 * 64 * 4);
    float* gi   = (float*)carve((size_t)NN * 192 * 4);
    float* gh   = (float*)carve((size_t)NN * 192 * 4);
    _Float16* he16 = (_Float16*)carve((size_t)EPAD * 128 * 2);
    _Float16* W2rT = (_Float16*)carve((size_t)64 * 8192 * 2);

    // ---- preamble ----
    hipMemsetAsync(deg, 0, (size_t)NN * 4, stream);
    transpose_kernel<<<128, 256, 0, stream>>>(gru_wih, gru_whh, lstm_wih, lstm_whh, lin1_w,
                                              gihT, ghhT, lihT, lhhT, l1T);
    lin0_kernel<<<(NN * 64 + 255) / 256, 256, 0, stream>>>(x, lin0_w, lin0_b, hv);
    deg_kernel<<<(EE + 255) / 256, 256, 0, stream>>>(ei, deg);
    he16_kernel<<<(EPAD * 128 + 255) / 256, 256, 0, stream>>>(ea, mlp_w1, mlp_b1, he16);
    w2rt_kernel<<<(64 * 8192 + 255) / 256, 256, 0, stream>>>(mlp_w2, W2rT);

    // ---- 3 message-passing + GRU iterations ----
    for (int it = 0; it < 3; it++) {
        hipMemsetAsync(agg, 0, (size_t)NN * 64 * 4, stream);
        hipMemsetAsync(xsum, 0, (size_t)NN * 64 * 4, stream);
        msg_gemm_kernel<<<EPAD / 256, 256, 0, stream>>>(hv, he16, W2rT, ei, agg, xsum);
        nnconv_kernel<<<(NN + 3) / 4, 256, 0, stream>>>(hv, agg, xsum, deg, root, mlp_b2, conv_b, mbuf);
        gates_kernel<<<(NN + 31) / 32, 192, 0, stream>>>(mbuf, gihT, gru_bih, gi);
        gates_kernel<<<(NN + 31) / 32, 192, 0, stream>>>(hv, ghhT, gru_bhh, gh);
        gru_combine_kernel<<<(NN * 64 + 255) / 256, 256, 0, stream>>>(gi, gh, hv);
    }

    // ---- Set2Set + readout ----
    set2set_kernel<<<BB, 256, 0, stream>>>(hv, lihT, lhhT, lstm_bih, lstm_bhh,
                                           l1T, lin1_b, lin2_w, lin2_b, out);
}

// Round 4
// 769.579 us; speedup vs baseline: 8.4274x; 1.5982x over previous
//
#include <hip/hip_runtime.h>
#include <hip/hip_bf16.h>

#define NN 50000
#define EE 100000
#define BB 2000
#define DIM 64
#define NF 14
#define EF 4
#define HID 128
#define EPAD 100096  // 391 * 256

typedef __attribute__((ext_vector_type(8))) _Float16 half8;   // 4 VGPRs
typedef __attribute__((ext_vector_type(4))) _Float16 half4;
typedef __attribute__((ext_vector_type(4))) float floatx4;    // MFMA C/D

// ---------------- weight transposes for set2set ----------------
__global__ void transpose_kernel(const float* __restrict__ lih, const float* __restrict__ lhh,
                                 const float* __restrict__ l1,
                                 float* __restrict__ lihT, float* __restrict__ lhhT,
                                 float* __restrict__ l1T) {
    int t = blockIdx.x * 256 + threadIdx.x;
    if (t < 256 * 128) { int j = t / 128, k = t % 128; lihT[k * 256 + j] = lih[t]; }
    if (t < 256 * 64) { int j = t / 64, k = t % 64; lhhT[k * 256 + j] = lhh[t]; }
    if (t < 64 * 128) { int d = t / 128, k = t % 128; l1T[k * 64 + d] = l1[t]; }
}

// ---------------- fused fp16 weight prep for node_fused ----------------
// W1h[n][k] (64x128): k<64 -> root[k][n], k>=64 -> b2[(k-64)*64+n]
// W2h[n2][k] (256x128): groups g=n2>>6, j=n2&63:
//   g0 (r-sum): k<64 wih[j][k], k>=64 whh[j][k-64]
//   g1 (z-sum): wih[64+j][k] / whh[64+j][k-64]
//   g2 (i_n):   k<64 wih[128+j][k], else 0
//   g3 (h_n):   k<64 0, else whh[128+j][k-64]
// fbias[256]: g0 bih[j]+bhh[j]; g1 bih[64+j]+bhh[64+j]; g2 bih[128+j]; g3 bhh[128+j]
__global__ void prep_gru_kernel(const float* __restrict__ root, const float* __restrict__ b2,
                                const float* __restrict__ wih, const float* __restrict__ whh,
                                const float* __restrict__ bih, const float* __restrict__ bhh,
                                _Float16* __restrict__ W1h, _Float16* __restrict__ W2h,
                                float* __restrict__ fbias) {
    int t = blockIdx.x * 256 + threadIdx.x;
    if (t < 64 * 128) {
        int n = t >> 7, k = t & 127;
        W1h[t] = (_Float16)(k < 64 ? root[k * 64 + n] : b2[(size_t)(k - 64) * 64 + n]);
    }
    if (t < 256 * 128) {
        int n2 = t >> 7, k = t & 127;
        int g = n2 >> 6, j = n2 & 63;
        float v;
        if (g == 0)      v = (k < 64) ? wih[j * 64 + k]         : whh[j * 64 + (k - 64)];
        else if (g == 1) v = (k < 64) ? wih[(64 + j) * 64 + k]  : whh[(64 + j) * 64 + (k - 64)];
        else if (g == 2) v = (k < 64) ? wih[(128 + j) * 64 + k] : 0.f;
        else             v = (k < 64) ? 0.f                     : whh[(128 + j) * 64 + (k - 64)];
        W2h[t] = (_Float16)v;
    }
    if (t < 256) {
        int g = t >> 6, j = t & 63;
        float v = (g == 0) ? bih[j] + bhh[j]
                : (g == 1) ? bih[64 + j] + bhh[64 + j]
                : (g == 2) ? bih[128 + j] : bhh[128 + j];
        fbias[t] = v;
    }
}

// ---------------- out0 = relu(x @ lin0_w.T + b) ----------------
__global__ void lin0_kernel(const float* __restrict__ x, const float* __restrict__ w,
                            const float* __restrict__ b, float* __restrict__ hv) {
    int t = blockIdx.x * 256 + threadIdx.x;
    if (t >= NN * 64) return;
    int n = t >> 6, d = t & 63;
    float acc = b[d];
    #pragma unroll
    for (int f = 0; f < NF; f++) acc += x[n * NF + f] * w[d * NF + f];
    hv[t] = fmaxf(acc, 0.f);
}

// ---------------- in-degree ----------------
__global__ void deg_kernel(const int* __restrict__ ei, float* __restrict__ deg) {
    int e = blockIdx.x * 256 + threadIdx.x;
    if (e < EE) atomicAdd(&deg[ei[EE + e]], 1.0f);
}

// ---------------- he16 = fp16(relu(edge_attr @ w1.T + b1)), zero-padded to EPAD ----------------
__global__ void he16_kernel(const float* __restrict__ ea, const float* __restrict__ w1,
                            const float* __restrict__ b1, _Float16* __restrict__ he) {
    int t = blockIdx.x * 256 + threadIdx.x;
    if (t >= EPAD * 128) return;
    int el = t >> 7, h = t & 127;
    float acc = 0.f;
    if (el < EE) {
        const float4 a = *(const float4*)(ea + (size_t)el * 4);
        const float4 w = *(const float4*)(w1 + h * 4);
        acc = fmaxf(b1[h] + a.x * w.x + a.y * w.y + a.z * w.z + a.w * w.w, 0.f);
    }
    he[t] = (_Float16)acc;
}

// ---------------- W2rT[o][i*128+h] = fp16(mlp_w2[(i*64+o)*128 + h]) ----------------
__global__ void w2rt_kernel(const float* __restrict__ w2, _Float16* __restrict__ W2rT) {
    int t = blockIdx.x * 256 + threadIdx.x;
    if (t >= 64 * 8192) return;
    int o = t >> 13, k = t & 8191, i = k >> 7, h = k & 127;
    W2rT[(size_t)o * 8192 + k] = (_Float16)w2[(size_t)(i * 64 + o) * 128 + h];
}

// ---------------- msg GEMM: msg = G @ W2rT^T, G generated in-register ----------------
__global__ __launch_bounds__(256, 2) void msg_gemm_kernel(
    const float* __restrict__ hv, const _Float16* __restrict__ he16,
    const _Float16* __restrict__ W2rT, const int* __restrict__ ei,
    float* __restrict__ agg, float* __restrict__ xsum) {
    __shared__ _Float16 sB[2][64 * 136];   // padded row stride 136
    __shared__ _Float16 sXs[256 * 68];     // [edge][i], padded stride 68
    __shared__ int sDst[256];
    const int t = threadIdx.x;
    const int eb = blockIdx.x * 256;
    const int lane = t & 63;
    const int w = t >> 6;
    const int col = lane & 15;
    const int quad = lane >> 4;

    if (t < 256) {
        int e = eb + t;
        sDst[t] = (e < EE) ? ei[EE + e] : 0;
    }
    #pragma unroll 4
    for (int rep = 0; rep < 16; rep++) {
        int idx = rep * 256 + t;
        int el = idx >> 4, d4 = idx & 15;
        int e = eb + el;
        float4 v = {0.f, 0.f, 0.f, 0.f};
        if (e < EE) {
            int src = ei[e];
            v = *(const float4*)(hv + (size_t)src * 64 + d4 * 4);
        }
        half4 h4 = {(_Float16)v.x, (_Float16)v.y, (_Float16)v.z, (_Float16)v.w};
        *(half4*)&sXs[el * 68 + d4 * 4] = h4;
    }

    half8 heReg[4][4];
    #pragma unroll
    for (int mt = 0; mt < 4; mt++) {
        int row = eb + w * 64 + mt * 16 + col;
        #pragma unroll
        for (int p = 0; p < 4; p++)
            heReg[mt][p] = *(const half8*)(he16 + (size_t)row * 128 + p * 32 + quad * 8);
    }

    floatx4 Cacc[4][4];
    #pragma unroll
    for (int mt = 0; mt < 4; mt++)
        #pragma unroll
        for (int nt = 0; nt < 4; nt++)
            Cacc[mt][nt] = (floatx4){0.f, 0.f, 0.f, 0.f};

    half8 pre[4];
    {
        #pragma unroll
        for (int rep = 0; rep < 4; rep++) {
            int idx = rep * 256 + t;
            int o = idx >> 4, sg = idx & 15;
            pre[rep] = *(const half8*)(W2rT + (size_t)o * 8192 + 0 * 128 + sg * 8);
        }
        #pragma unroll
        for (int rep = 0; rep < 4; rep++) {
            int idx = rep * 256 + t;
            int o = idx >> 4, sg = idx & 15;
            *(half8*)&sB[0][o * 136 + sg * 8] = pre[rep];
        }
    }
    __syncthreads();

    #pragma unroll 1
    for (int i = 0; i < 64; i++) {
        int buf = i & 1;
        if (i < 63) {
            #pragma unroll
            for (int rep = 0; rep < 4; rep++) {
                int idx = rep * 256 + t;
                int o = idx >> 4, sg = idx & 15;
                pre[rep] = *(const half8*)(W2rT + (size_t)o * 8192 + (i + 1) * 128 + sg * 8);
            }
        }
        _Float16 xsx[4];
        #pragma unroll
        for (int mt = 0; mt < 4; mt++)
            xsx[mt] = sXs[(w * 64 + mt * 16 + col) * 68 + i];
        #pragma unroll
        for (int ks = 0; ks < 4; ks++) {
            half8 bfr[4];
            #pragma unroll
            for (int nt = 0; nt < 4; nt++)
                bfr[nt] = *(const half8*)&sB[buf][(nt * 16 + col) * 136 + ks * 32 + quad * 8];
            #pragma unroll
            for (int mt = 0; mt < 4; mt++) {
                half8 afr = heReg[mt][ks] * xsx[mt];
                #pragma unroll
                for (int nt = 0; nt < 4; nt++)
                    Cacc[mt][nt] = __builtin_amdgcn_mfma_f32_16x16x32_f16(afr, bfr[nt], Cacc[mt][nt], 0, 0, 0);
            }
        }
        if (i < 63) {
            #pragma unroll
            for (int rep = 0; rep < 4; rep++) {
                int idx = rep * 256 + t;
                int o = idx >> 4, sg = idx & 15;
                *(half8*)&sB[buf ^ 1][o * 136 + sg * 8] = pre[rep];
            }
        }
        __syncthreads();
    }

    #pragma unroll
    for (int mt = 0; mt < 4; mt++) {
        #pragma unroll
        for (int r = 0; r < 4; r++) {
            int el = w * 64 + mt * 16 + quad * 4 + r;
            if (eb + el < EE) {
                float* ap = agg + (size_t)sDst[el] * 64 + col;
                #pragma unroll
                for (int nt = 0; nt < 4; nt++)
                    atomicAdd(ap + nt * 16, Cacc[mt][nt][r]);
            }
        }
    }
    #pragma unroll 4
    for (int rep = 0; rep < 64; rep++) {
        int idx = rep * 256 + t;
        int el = idx >> 6, d = idx & 63;
        if (eb + el < EE)
            atomicAdd(&xsum[(size_t)sDst[el] * 64 + d], (float)sXs[el * 68 + d]);
    }
}

// ---------------- fused node update: NNConv epilogue + GRU (MFMA) ----------------
// 64 nodes/block, 4 waves. Stage1: [hv | xsum/deg] @ [root;b2] + agg/deg + cb -> m (relu).
// Stage2: [m | hv] @ W2h (256 cols = {r-sum, z-sum, i_n, h_n}) -> gates -> h update in-register.
__global__ __launch_bounds__(256, 2) void node_fused_kernel(
    const float* __restrict__ hv_in, const float* __restrict__ agg,
    const float* __restrict__ xsum, const float* __restrict__ deg,
    const _Float16* __restrict__ W1h, const _Float16* __restrict__ W2h,
    const float* __restrict__ fbias, const float* __restrict__ cb,
    float* __restrict__ hv_out) {
    __shared__ _Float16 sA1[64 * 136];  // [node][k]: k<64 hv, k>=64 xsum/deg
    __shared__ _Float16 sA2[64 * 136];  // [node][k]: k<64 m, k>=64 hv
    __shared__ float sH[64 * 68];       // h_old fp32, reused for h_new
    __shared__ float sAgg[64 * 68];     // agg/deg fp32
    const int t = threadIdx.x;
    const int nb = blockIdx.x * 64;
    const int n = t >> 2, part = t & 3;
    {
        int gn = nb + n;
        bool valid = gn < NN;
        float inv = 1.f;
        if (valid) inv = 1.f / fmaxf(deg[gn], 1.f);
        #pragma unroll
        for (int c4 = 0; c4 < 4; c4++) {
            int d0 = part * 16 + c4 * 4;
            float4 hvv = {0.f, 0.f, 0.f, 0.f}, agv = {0.f, 0.f, 0.f, 0.f}, xsv = {0.f, 0.f, 0.f, 0.f};
            if (valid) {
                hvv = *(const float4*)(hv_in + (size_t)gn * 64 + d0);
                agv = *(const float4*)(agg + (size_t)gn * 64 + d0);
                xsv = *(const float4*)(xsum + (size_t)gn * 64 + d0);
            }
            agv.x *= inv; agv.y *= inv; agv.z *= inv; agv.w *= inv;
            xsv.x *= inv; xsv.y *= inv; xsv.z *= inv; xsv.w *= inv;
            half4 hvh = {(_Float16)hvv.x, (_Float16)hvv.y, (_Float16)hvv.z, (_Float16)hvv.w};
            half4 xsh = {(_Float16)xsv.x, (_Float16)xsv.y, (_Float16)xsv.z, (_Float16)xsv.w};
            *(half4*)&sA1[n * 136 + d0] = hvh;
            *(half4*)&sA1[n * 136 + 64 + d0] = xsh;
            *(half4*)&sA2[n * 136 + 64 + d0] = hvh;
            *(float4*)&sH[n * 68 + d0] = hvv;
            *(float4*)&sAgg[n * 68 + d0] = agv;
        }
    }
    __syncthreads();

    const int lane = t & 63, w = t >> 6;
    const int col = lane & 15, quad = lane >> 4;

    // ---- stage 1 ----
    floatx4 C1[4];
    #pragma unroll
    for (int nt = 0; nt < 4; nt++) {
        float b = cb[nt * 16 + col];
        C1[nt] = (floatx4){b, b, b, b};
    }
    #pragma unroll
    for (int ks = 0; ks < 4; ks++) {
        half8 a = *(const half8*)&sA1[(w * 16 + col) * 136 + ks * 32 + quad * 8];
        #pragma unroll
        for (int nt = 0; nt < 4; nt++) {
            half8 bfr = *(const half8*)(W1h + (size_t)(nt * 16 + col) * 128 + ks * 32 + quad * 8);
            C1[nt] = __builtin_amdgcn_mfma_f32_16x16x32_f16(a, bfr, C1[nt], 0, 0, 0);
        }
    }
    #pragma unroll
    for (int nt = 0; nt < 4; nt++) {
        #pragma unroll
        for (int r = 0; r < 4; r++) {
            int node = w * 16 + quad * 4 + r;
            int j = nt * 16 + col;
            float m = fmaxf(C1[nt][r] + sAgg[node * 68 + j], 0.f);
            sA2[node * 136 + j] = (_Float16)m;
        }
    }
    __syncthreads();

    // ---- stage 2 ----
    floatx4 C2[16];
    #pragma unroll
    for (int nt2 = 0; nt2 < 16; nt2++) {
        float b = fbias[nt2 * 16 + col];
        C2[nt2] = (floatx4){b, b, b, b};
    }
    #pragma unroll
    for (int ks = 0; ks < 4; ks++) {
        half8 a = *(const half8*)&sA2[(w * 16 + col) * 136 + ks * 32 + quad * 8];
        #pragma unroll
        for (int nt2 = 0; nt2 < 16; nt2++) {
            half8 bfr = *(const half8*)(W2h + (size_t)(nt2 * 16 + col) * 128 + ks * 32 + quad * 8);
            C2[nt2] = __builtin_amdgcn_mfma_f32_16x16x32_f16(a, bfr, C2[nt2], 0, 0, 0);
        }
    }
    // ---- combine (C2 groups: [0..3]=r-sum, [4..7]=z-sum, [8..11]=i_n, [12..15]=h_n; jt tiles j) ----
    float hnew[4][4];
    #pragma unroll
    for (int r = 0; r < 4; r++) {
        int node = w * 16 + quad * 4 + r;
        #pragma unroll
        for (int jt = 0; jt < 4; jt++) {
            int j = jt * 16 + col;
            float rr = 1.f / (1.f + expf(-C2[jt][r]));
            float zz = 1.f / (1.f + expf(-C2[4 + jt][r]));
            float ng = tanhf(C2[8 + jt][r] + rr * C2[12 + jt][r]);
            float hold = sH[node * 68 + j];
            hnew[r][jt] = (1.f - zz) * ng + zz * hold;
        }
    }
    __syncthreads();
    #pragma unroll
    for (int r = 0; r < 4; r++) {
        int node = w * 16 + quad * 4 + r;
        #pragma unroll
        for (int jt = 0; jt < 4; jt++)
            sH[node * 68 + jt * 16 + col] = hnew[r][jt];
    }
    __syncthreads();
    {
        int gn = nb + n;
        if (gn < NN) {
            #pragma unroll
            for (int c4 = 0; c4 < 4; c4++) {
                int d0 = part * 16 + c4 * 4;
                *(float4*)(hv_out + (size_t)gn * 64 + d0) = *(const float4*)&sH[n * 68 + d0];
            }
        }
    }
}

// ---------------- fused Set2Set (3 steps) + readout, one block per graph ----------------
__global__ __launch_bounds__(256) void set2set_kernel(
    const float* __restrict__ hv,
    const float* __restrict__ lihT, const float* __restrict__ lhhT,
    const float* __restrict__ l_bih, const float* __restrict__ l_bhh,
    const float* __restrict__ lin1T, const float* __restrict__ lin1_b,
    const float* __restrict__ lin2_w, const float* __restrict__ lin2_b,
    float* __restrict__ out) {
    __shared__ float outS[25 * 65];
    __shared__ float qs[128], qh[64], qc[64], gat[256], ew[32], aw[32], red[64];
    int g = blockIdx.x;
    int t = threadIdx.x;
    for (int p = t; p < 25 * 64; p += 256) {
        int j = p >> 6, i = p & 63;
        outS[j * 65 + i] = hv[(size_t)(g * 25 + j) * 64 + i];
    }
    if (t < 128) qs[t] = 0.f;
    if (t < 64) { qh[t] = 0.f; qc[t] = 0.f; }
    __syncthreads();
    for (int it = 0; it < 3; it++) {
        float acc = l_bih[t] + l_bhh[t];
        for (int k = 0; k < 128; k++) acc += qs[k] * lihT[k * 256 + t];
        for (int k = 0; k < 64; k++) acc += qh[k] * lhhT[k * 256 + t];
        gat[t] = acc;
        __syncthreads();
        if (t < 64) {
            float ig = 1.f / (1.f + expf(-gat[t]));
            float fg = 1.f / (1.f + expf(-gat[64 + t]));
            float gg = tanhf(gat[128 + t]);
            float og = 1.f / (1.f + expf(-gat[192 + t]));
            float c = fg * qc[t] + ig * gg;
            qc[t] = c;
            qh[t] = og * tanhf(c);
        }
        __syncthreads();
        if (t < 25) {
            float e = 0.f;
            for (int i = 0; i < 64; i++) e += outS[t * 65 + i] * qh[i];
            ew[t] = e;
        }
        __syncthreads();
        if (t == 0) {
            float mx = ew[0];
            for (int j = 1; j < 25; j++) mx = fmaxf(mx, ew[j]);
            float s = 0.f;
            for (int j = 0; j < 25; j++) { float a = expf(ew[j] - mx); aw[j] = a; s += a; }
            float inv = 1.f / s;
            for (int j = 0; j < 25; j++) aw[j] *= inv;
        }
        __syncthreads();
        if (t < 64) {
            float r = 0.f;
            for (int j = 0; j < 25; j++) r += aw[j] * outS[j * 65 + t];
            qs[t] = qh[t];
            qs[64 + t] = r;
        }
        __syncthreads();
    }
    if (t < 64) {
        float y1 = lin1_b[t];
        for (int k = 0; k < 128; k++) y1 += qs[k] * lin1T[k * 64 + t];
        y1 = fmaxf(y1, 0.f);
        red[t] = y1 * lin2_w[t];
    }
    __syncthreads();
    if (t == 0) {
        float y = lin2_b[0];
        for (int i = 0; i < 64; i++) y += red[i];
        out[g] = y;
    }
}

extern "C" void kernel_launch(void* const* d_in, const int* in_sizes, int n_in,
                              void* d_out, int out_size, void* d_ws, size_t ws_size,
                              hipStream_t stream) {
    const float* x        = (const float*)d_in[0];
    const float* ea       = (const float*)d_in[1];
    const int*   ei       = (const int*)  d_in[2];
    const float* lin0_w   = (const float*)d_in[4];
    const float* lin0_b   = (const float*)d_in[5];
    const float* mlp_w1   = (const float*)d_in[6];
    const float* mlp_b1   = (const float*)d_in[7];
    const float* mlp_w2   = (const float*)d_in[8];
    const float* mlp_b2   = (const float*)d_in[9];
    const float* root     = (const float*)d_in[10];
    const float* conv_b   = (const float*)d_in[11];
    const float* gru_wih  = (const float*)d_in[12];
    const float* gru_whh  = (const float*)d_in[13];
    const float* gru_bih  = (const float*)d_in[14];
    const float* gru_bhh  = (const float*)d_in[15];
    const float* lstm_wih = (const float*)d_in[16];
    const float* lstm_whh = (const float*)d_in[17];
    const float* lstm_bih = (const float*)d_in[18];
    const float* lstm_bhh = (const float*)d_in[19];
    const float* lin1_w   = (const float*)d_in[20];
    const float* lin1_b   = (const float*)d_in[21];
    const float* lin2_w   = (const float*)d_in[22];
    const float* lin2_b   = (const float*)d_in[23];
    float* out = (float*)d_out;

    // ---- workspace carve ----
    char* base = (char*)d_ws;
    size_t off = 0;
    auto carve = [&](size_t bytes) -> void* {
        void* r = base + off;
        off = (off + bytes + 255) & ~(size_t)255;
        return r;
    };
    float* hv   = (float*)carve((size_t)NN * 64 * 4);
    float* agg  = (float*)carve((size_t)NN * 64 * 4);
    float* xsum = (float*)carve((size_t)NN * 64 * 4);
    float* deg  = (float*)carve((size_t)NN * 4);
    float* lihT = (float*)carve(128 * 256 * 4);
    float* lhhT = (float*)carve(64 * 256 * 4);
    float* l1T  = (float*)carve(128 * 64 * 4);
    float* fbias = (float*)carve(256 * 4);
    _Float16* he16 = (_Float16*)carve((size_t)EPAD * 128 * 2);
    _Float16* W2rT = (_Float16*)carve((size_t)64 * 8192 * 2);
    _Float16* W1h  = (_Float16*)carve((size_t)64 * 128 * 2);
    _Float16* W2h  = (_Float16*)carve((size_t)256 * 128 * 2);

    // ---- preamble ----
    hipMemsetAsync(deg, 0, (size_t)NN * 4, stream);
    transpose_kernel<<<128, 256, 0, stream>>>(lstm_wih, lstm_whh, lin1_w, lihT, lhhT, l1T);
    prep_gru_kernel<<<128, 256, 0, stream>>>(root, mlp_b2, gru_wih, gru_whh, gru_bih, gru_bhh,
                                             W1h, W2h, fbias);
    lin0_kernel<<<(NN * 64 + 255) / 256, 256, 0, stream>>>(x, lin0_w, lin0_b, hv);
    deg_kernel<<<(EE + 255) / 256, 256, 0, stream>>>(ei, deg);
    he16_kernel<<<(EPAD * 128 + 255) / 256, 256, 0, stream>>>(ea, mlp_w1, mlp_b1, he16);
    w2rt_kernel<<<(64 * 8192 + 255) / 256, 256, 0, stream>>>(mlp_w2, W2rT);

    // ---- 3 message-passing + GRU iterations ----
    for (int it = 0; it < 3; it++) {
        hipMemsetAsync(agg, 0, (size_t)NN * 64 * 4, stream);
        hipMemsetAsync(xsum, 0, (size_t)NN * 64 * 4, stream);
        msg_gemm_kernel<<<EPAD / 256, 256, 0, stream>>>(hv, he16, W2rT, ei, agg, xsum);
        node_fused_kernel<<<(NN + 63) / 64, 256, 0, stream>>>(hv, agg, xsum, deg,
                                                              W1h, W2h, fbias, conv_b, hv);
    }

    // ---- Set2Set + readout ----
    set2set_kernel<<<BB, 256, 0, stream>>>(hv, lihT, lhhT, lstm_bih, lstm_bhh,
                                           l1T, lin1_b, lin2_w, lin2_b, out);
}

// Round 5
// 759.850 us; speedup vs baseline: 8.5353x; 1.0128x over previous
//
#include <hip/hip_runtime.h>
#include <hip/hip_bf16.h>

#define NN 50000
#define EE 100000
#define BB 2000
#define DIM 64
#define NF 14
#define EF 4
#define HID 128
#define EPAD 100096  // 391 * 256

typedef __attribute__((ext_vector_type(8))) _Float16 half8;   // 4 VGPRs
typedef __attribute__((ext_vector_type(4))) _Float16 half4;
typedef __attribute__((ext_vector_type(4))) float floatx4;    // MFMA C/D

// ---------------- weight transposes for set2set ----------------
__global__ void transpose_kernel(const float* __restrict__ lih, const float* __restrict__ lhh,
                                 const float* __restrict__ l1,
                                 float* __restrict__ lihT, float* __restrict__ lhhT,
                                 float* __restrict__ l1T) {
    int t = blockIdx.x * 256 + threadIdx.x;
    if (t < 256 * 128) { int j = t / 128, k = t % 128; lihT[k * 256 + j] = lih[t]; }
    if (t < 256 * 64) { int j = t / 64, k = t % 64; lhhT[k * 256 + j] = lhh[t]; }
    if (t < 64 * 128) { int d = t / 128, k = t % 128; l1T[k * 64 + d] = l1[t]; }
}

// ---------------- fused fp16 weight prep for node_fused ----------------
__global__ void prep_gru_kernel(const float* __restrict__ root, const float* __restrict__ b2,
                                const float* __restrict__ wih, const float* __restrict__ whh,
                                const float* __restrict__ bih, const float* __restrict__ bhh,
                                _Float16* __restrict__ W1h, _Float16* __restrict__ W2h,
                                float* __restrict__ fbias) {
    int t = blockIdx.x * 256 + threadIdx.x;
    if (t < 64 * 128) {
        int n = t >> 7, k = t & 127;
        W1h[t] = (_Float16)(k < 64 ? root[k * 64 + n] : b2[(size_t)(k - 64) * 64 + n]);
    }
    if (t < 256 * 128) {
        int n2 = t >> 7, k = t & 127;
        int g = n2 >> 6, j = n2 & 63;
        float v;
        if (g == 0)      v = (k < 64) ? wih[j * 64 + k]         : whh[j * 64 + (k - 64)];
        else if (g == 1) v = (k < 64) ? wih[(64 + j) * 64 + k]  : whh[(64 + j) * 64 + (k - 64)];
        else if (g == 2) v = (k < 64) ? wih[(128 + j) * 64 + k] : 0.f;
        else             v = (k < 64) ? 0.f                     : whh[(128 + j) * 64 + (k - 64)];
        W2h[t] = (_Float16)v;
    }
    if (t < 256) {
        int g = t >> 6, j = t & 63;
        float v = (g == 0) ? bih[j] + bhh[j]
                : (g == 1) ? bih[64 + j] + bhh[64 + j]
                : (g == 2) ? bih[128 + j] : bhh[128 + j];
        fbias[t] = v;
    }
}

// ---------------- out0 = relu(x @ lin0_w.T + b) ----------------
__global__ void lin0_kernel(const float* __restrict__ x, const float* __restrict__ w,
                            const float* __restrict__ b, float* __restrict__ hv) {
    int t = blockIdx.x * 256 + threadIdx.x;
    if (t >= NN * 64) return;
    int n = t >> 6, d = t & 63;
    float acc = b[d];
    #pragma unroll
    for (int f = 0; f < NF; f++) acc += x[n * NF + f] * w[d * NF + f];
    hv[t] = fmaxf(acc, 0.f);
}

// ---------------- in-degree ----------------
__global__ void deg_kernel(const int* __restrict__ ei, float* __restrict__ deg) {
    int e = blockIdx.x * 256 + threadIdx.x;
    if (e < EE) atomicAdd(&deg[ei[EE + e]], 1.0f);
}

// ---------------- he16 = fp16(relu(edge_attr @ w1.T + b1)), zero-padded to EPAD ----------------
__global__ void he16_kernel(const float* __restrict__ ea, const float* __restrict__ w1,
                            const float* __restrict__ b1, _Float16* __restrict__ he) {
    int t = blockIdx.x * 256 + threadIdx.x;
    if (t >= EPAD * 128) return;
    int el = t >> 7, h = t & 127;
    float acc = 0.f;
    if (el < EE) {
        const float4 a = *(const float4*)(ea + (size_t)el * 4);
        const float4 w = *(const float4*)(w1 + h * 4);
        acc = fmaxf(b1[h] + a.x * w.x + a.y * w.y + a.z * w.z + a.w * w.w, 0.f);
    }
    he[t] = (_Float16)acc;
}

// ---------------- W2rT[o][i*128+h] = fp16(mlp_w2[(i*64+o)*128 + h]) ----------------
__global__ void w2rt_kernel(const float* __restrict__ w2, _Float16* __restrict__ W2rT) {
    int t = blockIdx.x * 256 + threadIdx.x;
    if (t >= 64 * 8192) return;
    int o = t >> 13, k = t & 8191, i = k >> 7, h = k & 127;
    W2rT[(size_t)o * 8192 + k] = (_Float16)w2[(size_t)(i * 64 + o) * 128 + h];
}

// ---------------- msg GEMM: msg = G @ W2rT^T, G generated in-register ----------------
// sB is FRAGMENT-ORDER: unit index ((nt*4+ks)*64 + lane) of 16B -> reads AND writes are
// lane-sequential => zero bank conflicts (round-4 had ~8-way on stride-136 layout).
__global__ __launch_bounds__(256, 2) void msg_gemm_kernel(
    const float* __restrict__ hv, const _Float16* __restrict__ he16,
    const _Float16* __restrict__ W2rT, const int* __restrict__ ei,
    float* __restrict__ agg, float* __restrict__ xsum) {
    __shared__ _Float16 sB[2][16 * 64 * 8];   // [frag(nt*4+ks)][lane][8]
    __shared__ _Float16 sXs[256 * 68];        // [edge][i], padded stride 68
    __shared__ int sDst[256];
    const int t = threadIdx.x;
    const int eb = blockIdx.x * 256;
    const int lane = t & 63;
    const int w = t >> 6;
    const int col = lane & 15;
    const int quad = lane >> 4;

    if (t < 256) {
        int e = eb + t;
        sDst[t] = (e < EE) ? ei[EE + e] : 0;
    }
    #pragma unroll 4
    for (int rep = 0; rep < 16; rep++) {
        int idx = rep * 256 + t;
        int el = idx >> 4, d4 = idx & 15;
        int e = eb + el;
        float4 v = {0.f, 0.f, 0.f, 0.f};
        if (e < EE) {
            int src = ei[e];
            v = *(const float4*)(hv + (size_t)src * 64 + d4 * 4);
        }
        half4 h4 = {(_Float16)v.x, (_Float16)v.y, (_Float16)v.z, (_Float16)v.w};
        *(half4*)&sXs[el * 68 + d4 * 4] = h4;
    }

    half8 heReg[4][4];
    #pragma unroll
    for (int mt = 0; mt < 4; mt++) {
        int row = eb + w * 64 + mt * 16 + col;
        #pragma unroll
        for (int p = 0; p < 4; p++)
            heReg[mt][p] = *(const half8*)(he16 + (size_t)row * 128 + p * 32 + quad * 8);
    }

    floatx4 Cacc[4][4];
    #pragma unroll
    for (int mt = 0; mt < 4; mt++)
        #pragma unroll
        for (int nt = 0; nt < 4; nt++)
            Cacc[mt][nt] = (floatx4){0.f, 0.f, 0.f, 0.f};

    // staging: lane loads row (w*16+col), k-seg rep*32 + quad*8 of the current i-chunk,
    // writes to fragment slot ((w*4+rep)*64 + lane) -- lane-sequential, conflict-free.
    const size_t gbase = (size_t)(w * 16 + col) * 8192 + quad * 8;
    half8 pre[4];
    {
        #pragma unroll
        for (int rep = 0; rep < 4; rep++)
            pre[rep] = *(const half8*)(W2rT + gbase + 0 * 128 + rep * 32);
        #pragma unroll
        for (int rep = 0; rep < 4; rep++)
            *(half8*)&sB[0][((w * 4 + rep) * 64 + lane) * 8] = pre[rep];
    }
    __syncthreads();

    #pragma unroll 1
    for (int i = 0; i < 64; i++) {
        int buf = i & 1;
        if (i < 63) {
            #pragma unroll
            for (int rep = 0; rep < 4; rep++)
                pre[rep] = *(const half8*)(W2rT + gbase + (size_t)(i + 1) * 128 + rep * 32);
        }
        _Float16 xsx[4];
        #pragma unroll
        for (int mt = 0; mt < 4; mt++)
            xsx[mt] = sXs[(w * 64 + mt * 16 + col) * 68 + i];
        #pragma unroll
        for (int ks = 0; ks < 4; ks++) {
            half8 bfr[4];
            #pragma unroll
            for (int nt = 0; nt < 4; nt++)
                bfr[nt] = *(const half8*)&sB[buf][((nt * 4 + ks) * 64 + lane) * 8];
            #pragma unroll
            for (int mt = 0; mt < 4; mt++) {
                half8 afr = heReg[mt][ks] * xsx[mt];
                #pragma unroll
                for (int nt = 0; nt < 4; nt++)
                    Cacc[mt][nt] = __builtin_amdgcn_mfma_f32_16x16x32_f16(afr, bfr[nt], Cacc[mt][nt], 0, 0, 0);
            }
        }
        if (i < 63) {
            #pragma unroll
            for (int rep = 0; rep < 4; rep++)
                *(half8*)&sB[buf ^ 1][((w * 4 + rep) * 64 + lane) * 8] = pre[rep];
        }
        __syncthreads();
    }

    #pragma unroll
    for (int mt = 0; mt < 4; mt++) {
        #pragma unroll
        for (int r = 0; r < 4; r++) {
            int el = w * 64 + mt * 16 + quad * 4 + r;
            if (eb + el < EE) {
                float* ap = agg + (size_t)sDst[el] * 64 + col;
                #pragma unroll
                for (int nt = 0; nt < 4; nt++)
                    atomicAdd(ap + nt * 16, Cacc[mt][nt][r]);
            }
        }
    }
    #pragma unroll 4
    for (int rep = 0; rep < 64; rep++) {
        int idx = rep * 256 + t;
        int el = idx >> 6, d = idx & 63;
        if (eb + el < EE)
            atomicAdd(&xsum[(size_t)sDst[el] * 64 + d], (float)sXs[el * 68 + d]);
    }
}

// ---------------- fused node update: NNConv epilogue + GRU (MFMA) ----------------
// Also re-zeros agg/xsum after consuming them (saves per-iteration memset dispatches).
__global__ __launch_bounds__(256, 2) void node_fused_kernel(
    const float* __restrict__ hv_in, float* __restrict__ agg,
    float* __restrict__ xsum, const float* __restrict__ deg,
    const _Float16* __restrict__ W1h, const _Float16* __restrict__ W2h,
    const float* __restrict__ fbias, const float* __restrict__ cb,
    float* __restrict__ hv_out) {
    __shared__ _Float16 sA1[64 * 136];  // [node][k]: k<64 hv, k>=64 xsum/deg
    __shared__ _Float16 sA2[64 * 136];  // [node][k]: k<64 m, k>=64 hv
    __shared__ float sH[64 * 68];       // h_old fp32, reused for h_new
    __shared__ float sAgg[64 * 68];     // agg/deg fp32
    const int t = threadIdx.x;
    const int nb = blockIdx.x * 64;
    const int n = t >> 2, part = t & 3;
    {
        int gn = nb + n;
        bool valid = gn < NN;
        float inv = 1.f;
        if (valid) inv = 1.f / fmaxf(deg[gn], 1.f);
        #pragma unroll
        for (int c4 = 0; c4 < 4; c4++) {
            int d0 = part * 16 + c4 * 4;
            float4 hvv = {0.f, 0.f, 0.f, 0.f}, agv = {0.f, 0.f, 0.f, 0.f}, xsv = {0.f, 0.f, 0.f, 0.f};
            if (valid) {
                hvv = *(const float4*)(hv_in + (size_t)gn * 64 + d0);
                agv = *(const float4*)(agg + (size_t)gn * 64 + d0);
                xsv = *(const float4*)(xsum + (size_t)gn * 64 + d0);
            }
            agv.x *= inv; agv.y *= inv; agv.z *= inv; agv.w *= inv;
            xsv.x *= inv; xsv.y *= inv; xsv.z *= inv; xsv.w *= inv;
            half4 hvh = {(_Float16)hvv.x, (_Float16)hvv.y, (_Float16)hvv.z, (_Float16)hvv.w};
            half4 xsh = {(_Float16)xsv.x, (_Float16)xsv.y, (_Float16)xsv.z, (_Float16)xsv.w};
            *(half4*)&sA1[n * 136 + d0] = hvh;
            *(half4*)&sA1[n * 136 + 64 + d0] = xsh;
            *(half4*)&sA2[n * 136 + 64 + d0] = hvh;
            *(float4*)&sH[n * 68 + d0] = hvv;
            *(float4*)&sAgg[n * 68 + d0] = agv;
        }
        // re-zero agg/xsum for the next msg_gemm launch
        if (valid) {
            float4 z = {0.f, 0.f, 0.f, 0.f};
            #pragma unroll
            for (int c4 = 0; c4 < 4; c4++) {
                int d0 = part * 16 + c4 * 4;
                *(float4*)(agg + (size_t)gn * 64 + d0) = z;
                *(float4*)(xsum + (size_t)gn * 64 + d0) = z;
            }
        }
    }
    __syncthreads();

    const int lane = t & 63, w = t >> 6;
    const int col = lane & 15, quad = lane >> 4;

    // ---- stage 1 ----
    floatx4 C1[4];
    #pragma unroll
    for (int nt = 0; nt < 4; nt++) {
        float b = cb[nt * 16 + col];
        C1[nt] = (floatx4){b, b, b, b};
    }
    #pragma unroll
    for (int ks = 0; ks < 4; ks++) {
        half8 a = *(const half8*)&sA1[(w * 16 + col) * 136 + ks * 32 + quad * 8];
        #pragma unroll
        for (int nt = 0; nt < 4; nt++) {
            half8 bfr = *(const half8*)(W1h + (size_t)(nt * 16 + col) * 128 + ks * 32 + quad * 8);
            C1[nt] = __builtin_amdgcn_mfma_f32_16x16x32_f16(a, bfr, C1[nt], 0, 0, 0);
        }
    }
    #pragma unroll
    for (int nt = 0; nt < 4; nt++) {
        #pragma unroll
        for (int r = 0; r < 4; r++) {
            int node = w * 16 + quad * 4 + r;
            int j = nt * 16 + col;
            float m = fmaxf(C1[nt][r] + sAgg[node * 68 + j], 0.f);
            sA2[node * 136 + j] = (_Float16)m;
        }
    }
    __syncthreads();

    // ---- stage 2 ----
    floatx4 C2[16];
    #pragma unroll
    for (int nt2 = 0; nt2 < 16; nt2++) {
        float b = fbias[nt2 * 16 + col];
        C2[nt2] = (floatx4){b, b, b, b};
    }
    #pragma unroll
    for (int ks = 0; ks < 4; ks++) {
        half8 a = *(const half8*)&sA2[(w * 16 + col) * 136 + ks * 32 + quad * 8];
        #pragma unroll
        for (int nt2 = 0; nt2 < 16; nt2++) {
            half8 bfr = *(const half8*)(W2h + (size_t)(nt2 * 16 + col) * 128 + ks * 32 + quad * 8);
            C2[nt2] = __builtin_amdgcn_mfma_f32_16x16x32_f16(a, bfr, C2[nt2], 0, 0, 0);
        }
    }
    float hnew[4][4];
    #pragma unroll
    for (int r = 0; r < 4; r++) {
        int node = w * 16 + quad * 4 + r;
        #pragma unroll
        for (int jt = 0; jt < 4; jt++) {
            int j = jt * 16 + col;
            float rr = 1.f / (1.f + expf(-C2[jt][r]));
            float zz = 1.f / (1.f + expf(-C2[4 + jt][r]));
            float ng = tanhf(C2[8 + jt][r] + rr * C2[12 + jt][r]);
            float hold = sH[node * 68 + j];
            hnew[r][jt] = (1.f - zz) * ng + zz * hold;
        }
    }
    __syncthreads();
    #pragma unroll
    for (int r = 0; r < 4; r++) {
        int node = w * 16 + quad * 4 + r;
        #pragma unroll
        for (int jt = 0; jt < 4; jt++)
            sH[node * 68 + jt * 16 + col] = hnew[r][jt];
    }
    __syncthreads();
    {
        int gn = nb + n;
        if (gn < NN) {
            #pragma unroll
            for (int c4 = 0; c4 < 4; c4++) {
                int d0 = part * 16 + c4 * 4;
                *(float4*)(hv_out + (size_t)gn * 64 + d0) = *(const float4*)&sH[n * 68 + d0];
            }
        }
    }
}

// ---------------- fused Set2Set (3 steps) + readout, one block per graph ----------------
__global__ __launch_bounds__(256) void set2set_kernel(
    const float* __restrict__ hv,
    const float* __restrict__ lihT, const float* __restrict__ lhhT,
    const float* __restrict__ l_bih, const float* __restrict__ l_bhh,
    const float* __restrict__ lin1T, const float* __restrict__ lin1_b,
    const float* __restrict__ lin2_w, const float* __restrict__ lin2_b,
    float* __restrict__ out) {
    __shared__ float outS[25 * 65];
    __shared__ float qs[128], qh[64], qc[64], gat[256], ew[32], aw[32], red[64];
    int g = blockIdx.x;
    int t = threadIdx.x;
    for (int p = t; p < 25 * 64; p += 256) {
        int j = p >> 6, i = p & 63;
        outS[j * 65 + i] = hv[(size_t)(g * 25 + j) * 64 + i];
    }
    if (t < 128) qs[t] = 0.f;
    if (t < 64) { qh[t] = 0.f; qc[t] = 0.f; }
    __syncthreads();
    for (int it = 0; it < 3; it++) {
        float acc = l_bih[t] + l_bhh[t];
        for (int k = 0; k < 128; k++) acc += qs[k] * lihT[k * 256 + t];
        for (int k = 0; k < 64; k++) acc += qh[k] * lhhT[k * 256 + t];
        gat[t] = acc;
        __syncthreads();
        if (t < 64) {
            float ig = 1.f / (1.f + expf(-gat[t]));
            float fg = 1.f / (1.f + expf(-gat[64 + t]));
            float gg = tanhf(gat[128 + t]);
            float og = 1.f / (1.f + expf(-gat[192 + t]));
            float c = fg * qc[t] + ig * gg;
            qc[t] = c;
            qh[t] = og * tanhf(c);
        }
        __syncthreads();
        if (t < 25) {
            float e = 0.f;
            for (int i = 0; i < 64; i++) e += outS[t * 65 + i] * qh[i];
            ew[t] = e;
        }
        __syncthreads();
        if (t == 0) {
            float mx = ew[0];
            for (int j = 1; j < 25; j++) mx = fmaxf(mx, ew[j]);
            float s = 0.f;
            for (int j = 0; j < 25; j++) { float a = expf(ew[j] - mx); aw[j] = a; s += a; }
            float inv = 1.f / s;
            for (int j = 0; j < 25; j++) aw[j] *= inv;
        }
        __syncthreads();
        if (t < 64) {
            float r = 0.f;
            for (int j = 0; j < 25; j++) r += aw[j] * outS[j * 65 + t];
            qs[t] = qh[t];
            qs[64 + t] = r;
        }
        __syncthreads();
    }
    if (t < 64) {
        float y1 = lin1_b[t];
        for (int k = 0; k < 128; k++) y1 += qs[k] * lin1T[k * 64 + t];
        y1 = fmaxf(y1, 0.f);
        red[t] = y1 * lin2_w[t];
    }
    __syncthreads();
    if (t == 0) {
        float y = lin2_b[0];
        for (int i = 0; i < 64; i++) y += red[i];
        out[g] = y;
    }
}

extern "C" void kernel_launch(void* const* d_in, const int* in_sizes, int n_in,
                              void* d_out, int out_size, void* d_ws, size_t ws_size,
                              hipStream_t stream) {
    const float* x        = (const float*)d_in[0];
    const float* ea       = (const float*)d_in[1];
    const int*   ei       = (const int*)  d_in[2];
    const float* lin0_w   = (const float*)d_in[4];
    const float* lin0_b   = (const float*)d_in[5];
    const float* mlp_w1   = (const float*)d_in[6];
    const float* mlp_b1   = (const float*)d_in[7];
    const float* mlp_w2   = (const float*)d_in[8];
    const float* mlp_b2   = (const float*)d_in[9];
    const float* root     = (const float*)d_in[10];
    const float* conv_b   = (const float*)d_in[11];
    const float* gru_wih  = (const float*)d_in[12];
    const float* gru_whh  = (const float*)d_in[13];
    const float* gru_bih  = (const float*)d_in[14];
    const float* gru_bhh  = (const float*)d_in[15];
    const float* lstm_wih = (const float*)d_in[16];
    const float* lstm_whh = (const float*)d_in[17];
    const float* lstm_bih = (const float*)d_in[18];
    const float* lstm_bhh = (const float*)d_in[19];
    const float* lin1_w   = (const float*)d_in[20];
    const float* lin1_b   = (const float*)d_in[21];
    const float* lin2_w   = (const float*)d_in[22];
    const float* lin2_b   = (const float*)d_in[23];
    float* out = (float*)d_out;

    // ---- workspace carve ----
    char* base = (char*)d_ws;
    size_t off = 0;
    auto carve = [&](size_t bytes) -> void* {
        void* r = base + off;
        off = (off + bytes + 255) & ~(size_t)255;
        return r;
    };
    float* hv   = (float*)carve((size_t)NN * 64 * 4);
    float* agg  = (float*)carve((size_t)NN * 64 * 4);   // agg+xsum adjacent: one memset
    float* xsum = (float*)carve((size_t)NN * 64 * 4);
    float* deg  = (float*)carve((size_t)NN * 4);
    float* lihT = (float*)carve(128 * 256 * 4);
    float* lhhT = (float*)carve(64 * 256 * 4);
    float* l1T  = (float*)carve(128 * 64 * 4);
    float* fbias = (float*)carve(256 * 4);
    _Float16* he16 = (_Float16*)carve((size_t)EPAD * 128 * 2);
    _Float16* W2rT = (_Float16*)carve((size_t)64 * 8192 * 2);
    _Float16* W1h  = (_Float16*)carve((size_t)64 * 128 * 2);
    _Float16* W2h  = (_Float16*)carve((size_t)256 * 128 * 2);

    // ---- preamble ----
    hipMemsetAsync(deg, 0, (size_t)NN * 4, stream);
    hipMemsetAsync(agg, 0, (size_t)NN * 64 * 4 * 2, stream);  // agg + xsum (adjacent)
    transpose_kernel<<<128, 256, 0, stream>>>(lstm_wih, lstm_whh, lin1_w, lihT, lhhT, l1T);
    prep_gru_kernel<<<128, 256, 0, stream>>>(root, mlp_b2, gru_wih, gru_whh, gru_bih, gru_bhh,
                                             W1h, W2h, fbias);
    lin0_kernel<<<(NN * 64 + 255) / 256, 256, 0, stream>>>(x, lin0_w, lin0_b, hv);
    deg_kernel<<<(EE + 255) / 256, 256, 0, stream>>>(ei, deg);
    he16_kernel<<<(EPAD * 128 + 255) / 256, 256, 0, stream>>>(ea, mlp_w1, mlp_b1, he16);
    w2rt_kernel<<<(64 * 8192 + 255) / 256, 256, 0, stream>>>(mlp_w2, W2rT);

    // ---- 3 message-passing + GRU iterations (node_fused re-zeros agg/xsum) ----
    for (int it = 0; it < 3; it++) {
        msg_gemm_kernel<<<EPAD / 256, 256, 0, stream>>>(hv, he16, W2rT, ei, agg, xsum);
        node_fused_kernel<<<(NN + 63) / 64, 256, 0, stream>>>(hv, agg, xsum, deg,
                                                              W1h, W2h, fbias, conv_b, hv);
    }

    // ---- Set2Set + readout ----
    set2set_kernel<<<BB, 256, 0, stream>>>(hv, lihT, lhhT, lstm_bih, lstm_bhh,
                                           l1T, lin1_b, lin2_w, lin2_b, out);
}